// Round 12
// baseline (1471.101 us; speedup 1.0000x reference)
//
#include <hip/hip_runtime.h>

#define MTOT 131072   // b*n
#define NB   65536    // n per batch

typedef __attribute__((ext_vector_type(8))) __bf16 bf16x8;
typedef __attribute__((ext_vector_type(4))) __bf16 bf16x4;
typedef __attribute__((ext_vector_type(4))) float  f32x4;

// ---------------------------------------------------------------- pmin
__global__ void pmin_init_kernel(float* pmin){
    if (threadIdx.x < 6) pmin[threadIdx.x] = 2.0f;   // p in [0,1)
}

__global__ void pmin_kernel(const float* __restrict__ p, float* __restrict__ pmin){
    int bi = blockIdx.y;
    float m0 = 2.f, m1 = 2.f, m2 = 2.f;
    for (int ni = blockIdx.x * blockDim.x + threadIdx.x; ni < NB; ni += gridDim.x * blockDim.x){
        const float* pp = p + ((size_t)bi * NB + ni) * 3;
        m0 = fminf(m0, pp[0]); m1 = fminf(m1, pp[1]); m2 = fminf(m2, pp[2]);
    }
    #pragma unroll
    for (int o = 32; o > 0; o >>= 1){
        m0 = fminf(m0, __shfl_down(m0, o, 64));
        m1 = fminf(m1, __shfl_down(m1, o, 64));
        m2 = fminf(m2, __shfl_down(m2, o, 64));
    }
    if ((threadIdx.x & 63) == 0){
        atomicMin((int*)(pmin + bi*3 + 0), __float_as_int(m0));
        atomicMin((int*)(pmin + bi*3 + 1), __float_as_int(m1));
        atomicMin((int*)(pmin + bi*3 + 2), __float_as_int(m2));
    }
}

// ---------------------------------------------------------------- voxel scatter (atomicMax of ids)
// f64 voxelization (floor(p/g) in double) matches the numpy f64 reference bit-exactly.
template<int USE_LDS>
__global__ void scatter_kernel(const float* __restrict__ p, const float* __restrict__ pmin,
                               int* __restrict__ vgrid, int* __restrict__ gcbuf,
                               double gd, int D){
    extern __shared__ int lgrid[];
    int m  = blockIdx.x * blockDim.x + threadIdx.x;
    int bi = m >> 16;
    double px = (double)p[m*3], py = (double)p[m*3+1], pz = (double)p[m*3+2];
    int gx = (int)floor(px / gd) - (int)floor((double)pmin[bi*3+0] / gd);
    int gy = (int)floor(py / gd) - (int)floor((double)pmin[bi*3+1] / gd);
    int gz = (int)floor(pz / gd) - (int)floor((double)pmin[bi*3+2] / gd);
    gcbuf[m] = (gx << 20) | (gy << 10) | gz;
    int cell = (gx * D + gy) * D + gz;

    if (!USE_LDS){
        atomicMax(vgrid + bi * D * D * D + cell, m);
        return;
    }
    int ncell = D * D * D;
    for (int c = threadIdx.x; c < ncell; c += 256) lgrid[c] = -1;
    __syncthreads();
    atomicMax(&lgrid[cell], m);
    __syncthreads();
    int* vg = vgrid + bi * ncell;
    for (int c = threadIdx.x; c < ncell; c += 256){
        int v = lgrid[c];
        if (v >= 0) atomicMax(vg + c, v);
    }
}

// ---------------------------------------------------------------- 27-tap neighbor table
__global__ void nbr_kernel(const int* __restrict__ gcbuf, const int* __restrict__ vgrid,
                           int* __restrict__ nbr, int D){
    int m  = blockIdx.x * blockDim.x + threadIdx.x;
    int bi = m >> 16;
    int pk = gcbuf[m];
    int gx = pk >> 20, gy = (pk >> 10) & 1023, gz = pk & 1023;
    #pragma unroll
    for (int k = 0; k < 27; k++){
        int v;
        if (k == 13){
            v = m;
        } else {
            int x = gx + (k/9) - 1;
            int y = gy + ((k/3)%3) - 1;
            int z = gz + (k%3) - 1;
            if (x < 0 || y < 0 || z < 0 || x >= D || y >= D || z >= D) v = -1;
            else v = vgrid[((bi * D + x) * D + y) * D + z];
        }
        nbr[k * MTOT + m] = v;
    }
}

// ---------------------------------------------------------------- W_conv -> transposed bf16 hi/lo planes
__global__ void wcv_kernel(const float* __restrict__ w_conv,
                           __bf16* __restrict__ wth, __bf16* __restrict__ wtl){
    int o = blockIdx.x * 256 + threadIdx.x;          // 442368 total
    int cv = o / 27648, r = o % 27648;
    int k = r / 1024, q = r % 1024, c = q / 32, j = q % 32;
    float x = w_conv[cv*27648 + k*1024 + j*32 + c];
    __bf16 hi = (__bf16)x;
    wth[o] = hi;
    wtl[o] = (__bf16)(x - (float)hi);
}

// ---------------------------------------------------------------- w2 -> [kc][c(128)][j(32)] bf16 hi/lo
__global__ void w2t_kernel(const float* __restrict__ w2,
                           __bf16* __restrict__ w2th, __bf16* __restrict__ w2tl){
    int o = blockIdx.x * 256 + threadIdx.x;          // 32768 total
    int kc = o >> 12, r = o & 4095, c = r >> 5, j = r & 31;
    float x = w2[(kc*32 + j)*128 + c];
    __bf16 hi = (__bf16)x;
    w2th[o] = hi;
    w2tl[o] = (__bf16)(x - (float)hi);
}

// ---------------------------------------------------------------- zero rows (gather target for masked taps)
__global__ void zero_rows_kernel(__bf16* __restrict__ h0i, __bf16* __restrict__ h1i){
    int t = threadIdx.x;
    if (t < 64)       h0i[(size_t)MTOT*64 + t] = (__bf16)0.0f;
    else              h1i[(size_t)MTOT*64 + (t-64)] = (__bf16)0.0f;
}

// ---------------------------------------------------------------- fused mlp1+mlp -> INTERLEAVED plane [pt][hi32|lo32]
__global__ void mlp_scale_i_kernel(const float* __restrict__ p, const float* __restrict__ w1,
                                   const float* __restrict__ b1,
                                   const float* __restrict__ w, const float* __restrict__ b,
                                   __bf16* __restrict__ h0i){
    int t = blockIdx.x * blockDim.x + threadIdx.x;
    int c = t & 31, m = t >> 5;
    float x = p[m*3+0], y = p[m*3+1], z = p[m*3+2];
    float acc = b[c];
    #pragma unroll
    for (int j = 0; j < 32; j++){
        float ptsj = b1[j] + x * w1[j] + y * w1[32 + j] + z * w1[64 + j];
        acc += ptsj * w[j*32 + c];
    }
    __bf16 hi = (__bf16)acc;
    h0i[(size_t)m*64 + c]      = hi;
    h0i[(size_t)m*64 + 32 + c] = (__bf16)(acc - (float)hi);
}

// ---------------------------------------------------------------- split-plane mlp (fallback path)
__global__ void mlp_scale_s_kernel(const float* __restrict__ p, const float* __restrict__ w1,
                                   const float* __restrict__ b1,
                                   const float* __restrict__ w, const float* __restrict__ b,
                                   __bf16* __restrict__ h0h, __bf16* __restrict__ h0l){
    int t = blockIdx.x * blockDim.x + threadIdx.x;
    int c = t & 31, m = t >> 5;
    float x = p[m*3+0], y = p[m*3+1], z = p[m*3+2];
    float acc = b[c];
    #pragma unroll
    for (int j = 0; j < 32; j++){
        float ptsj = b1[j] + x * w1[j] + y * w1[32 + j] + z * w1[64 + j];
        acc += ptsj * w[j*32 + c];
    }
    __bf16 hi = (__bf16)acc;
    h0h[t] = hi;
    h0l[t] = (__bf16)(acc - (float)hi);
}

// ================================================================ BIG-WS PATH
// conv4: 4-way tap split + 2-stage pipeline, INTERLEAVED planes + zero-row.
//  - interleave: hi+lo of a point share one 128-B line (r11 split planes put them
//    8 MB apart -> 2x distinct cache lines per gather).
//  - zero-row: masked taps gather row MTOT (all zeros) -> 2 index-selects/tap
//    instead of 16 data-cndmasks. Arithmetic identical (A=0 either way).
// MODE 0: h1 plane = conv(f) + f
// MODE 1: v plane  = conv(f) + f + h0      (w2 GEMM deferred to mlp2_kernel)
template<int MODE>
__global__ __launch_bounds__(256)
void conv4_kernel(const __bf16* __restrict__ f,
                  const __bf16* __restrict__ wth, const __bf16* __restrict__ wtl,
                  const float* __restrict__ bias, const int* __restrict__ nbr,
                  const __bf16* __restrict__ r2,
                  __bf16* __restrict__ outp)
{
    __shared__ float buf0[32][33], buf1[32][33];
    int tid  = threadIdx.x;
    int lane = tid & 63, w = tid >> 6;
    int col  = lane & 15, kq = lane >> 4;
    int ptA  = blockIdx.x * 32 + col, ptB = ptA + 16;
    const int fragoff = kq * 8;

    f32x4 acc00, acc01, acc10, acc11;
    if (w == 0){
        float bv0 = bias[col], bv1 = bias[col + 16];
        acc00 = (f32x4){bv0,bv0,bv0,bv0}; acc01 = (f32x4){bv1,bv1,bv1,bv1};
        acc10 = (f32x4){bv0,bv0,bv0,bv0}; acc11 = (f32x4){bv1,bv1,bv1,bv1};
    } else {
        acc00 = (f32x4){0,0,0,0}; acc01 = (f32x4){0,0,0,0};
        acc10 = (f32x4){0,0,0,0}; acc11 = (f32x4){0,0,0,0};
    }

    int k0 = w * 7, k1 = (k0 + 7 < 27) ? k0 + 7 : 27;

    // prologue: rows for k0, ids for k0+1 (masked -> zero row MTOT)
    int ic = nbr[k0 * MTOT + ptA]; ic = (ic < 0) ? MTOT : ic;
    int jc = nbr[k0 * MTOT + ptB]; jc = (jc < 0) ? MTOT : jc;
    int in_ = MTOT, jn = MTOT;
    if (k0 + 1 < k1){
        in_ = nbr[(k0+1) * MTOT + ptA]; in_ = (in_ < 0) ? MTOT : in_;
        jn  = nbr[(k0+1) * MTOT + ptB]; jn  = (jn  < 0) ? MTOT : jn;
    }
    size_t oc0 = (size_t)ic * 64 + fragoff;
    size_t oc1 = (size_t)jc * 64 + fragoff;
    bf16x8 a0h = *(const bf16x8*)(f + oc0);
    bf16x8 a0l = *(const bf16x8*)(f + oc0 + 32);
    bf16x8 a1h = *(const bf16x8*)(f + oc1);
    bf16x8 a1l = *(const bf16x8*)(f + oc1 + 32);

    #pragma unroll 1
    for (int k = k0; k < k1; k++){
        int in2 = MTOT, jn2 = MTOT;
        if (k + 2 < k1){
            in2 = nbr[(k+2) * MTOT + ptA]; in2 = (in2 < 0) ? MTOT : in2;
            jn2 = nbr[(k+2) * MTOT + ptB]; jn2 = (jn2 < 0) ? MTOT : jn2;
        }
        size_t on0 = (size_t)in_ * 64 + fragoff;
        size_t on1 = (size_t)jn  * 64 + fragoff;
        bf16x8 na0h = *(const bf16x8*)(f + on0);
        bf16x8 na0l = *(const bf16x8*)(f + on0 + 32);
        bf16x8 na1h = *(const bf16x8*)(f + on1);
        bf16x8 na1l = *(const bf16x8*)(f + on1 + 32);

        const __bf16* wb = wth + (size_t)k*1024 + col*32 + fragoff;
        const __bf16* wc = wtl + (size_t)k*1024 + col*32 + fragoff;
        bf16x8 b0h = *(const bf16x8*)(wb);
        bf16x8 b1h = *(const bf16x8*)(wb + 512);
        bf16x8 b0l = *(const bf16x8*)(wc);
        bf16x8 b1l = *(const bf16x8*)(wc + 512);

        acc00 = __builtin_amdgcn_mfma_f32_16x16x32_bf16(a0h, b0h, acc00, 0,0,0);
        acc00 = __builtin_amdgcn_mfma_f32_16x16x32_bf16(a0h, b0l, acc00, 0,0,0);
        acc00 = __builtin_amdgcn_mfma_f32_16x16x32_bf16(a0l, b0h, acc00, 0,0,0);
        acc01 = __builtin_amdgcn_mfma_f32_16x16x32_bf16(a0h, b1h, acc01, 0,0,0);
        acc01 = __builtin_amdgcn_mfma_f32_16x16x32_bf16(a0h, b1l, acc01, 0,0,0);
        acc01 = __builtin_amdgcn_mfma_f32_16x16x32_bf16(a0l, b1h, acc01, 0,0,0);
        acc10 = __builtin_amdgcn_mfma_f32_16x16x32_bf16(a1h, b0h, acc10, 0,0,0);
        acc10 = __builtin_amdgcn_mfma_f32_16x16x32_bf16(a1h, b0l, acc10, 0,0,0);
        acc10 = __builtin_amdgcn_mfma_f32_16x16x32_bf16(a1l, b0h, acc10, 0,0,0);
        acc11 = __builtin_amdgcn_mfma_f32_16x16x32_bf16(a1h, b1h, acc11, 0,0,0);
        acc11 = __builtin_amdgcn_mfma_f32_16x16x32_bf16(a1h, b1l, acc11, 0,0,0);
        acc11 = __builtin_amdgcn_mfma_f32_16x16x32_bf16(a1l, b1h, acc11, 0,0,0);

        a0h = na0h; a0l = na0l; a1h = na1h; a1l = na1l;
        in_ = in2; jn = jn2;
    }

    // tree combine: final = (bias+T0+T2) + (T1+T3)
    if (w == 2){
        #pragma unroll
        for (int r = 0; r < 4; r++){
            buf0[kq*4 + r][col]           = acc00[r];
            buf0[kq*4 + r][col + 16]      = acc01[r];
            buf0[16 + kq*4 + r][col]      = acc10[r];
            buf0[16 + kq*4 + r][col + 16] = acc11[r];
        }
    } else if (w == 3){
        #pragma unroll
        for (int r = 0; r < 4; r++){
            buf1[kq*4 + r][col]           = acc00[r];
            buf1[kq*4 + r][col + 16]      = acc01[r];
            buf1[16 + kq*4 + r][col]      = acc10[r];
            buf1[16 + kq*4 + r][col + 16] = acc11[r];
        }
    }
    __syncthreads();
    if (w == 0){
        #pragma unroll
        for (int r = 0; r < 4; r++){
            acc00[r] += buf0[kq*4 + r][col];
            acc01[r] += buf0[kq*4 + r][col + 16];
            acc10[r] += buf0[16 + kq*4 + r][col];
            acc11[r] += buf0[16 + kq*4 + r][col + 16];
        }
    } else if (w == 1){
        #pragma unroll
        for (int r = 0; r < 4; r++){
            acc00[r] += buf1[kq*4 + r][col];
            acc01[r] += buf1[kq*4 + r][col + 16];
            acc10[r] += buf1[16 + kq*4 + r][col];
            acc11[r] += buf1[16 + kq*4 + r][col + 16];
        }
    }
    __syncthreads();
    if (w == 1){
        #pragma unroll
        for (int r = 0; r < 4; r++){
            buf1[kq*4 + r][col]           = acc00[r];
            buf1[kq*4 + r][col + 16]      = acc01[r];
            buf1[16 + kq*4 + r][col]      = acc10[r];
            buf1[16 + kq*4 + r][col + 16] = acc11[r];
        }
    }
    __syncthreads();
    if (w == 0){
        #pragma unroll
        for (int r = 0; r < 4; r++){
            buf0[kq*4 + r][col]           = acc00[r] + buf1[kq*4 + r][col];
            buf0[kq*4 + r][col + 16]      = acc01[r] + buf1[kq*4 + r][col + 16];
            buf0[16 + kq*4 + r][col]      = acc10[r] + buf1[16 + kq*4 + r][col];
            buf0[16 + kq*4 + r][col + 16] = acc11[r] + buf1[16 + kq*4 + r][col + 16];
        }
    }
    __syncthreads();

    // epilogue: 32 pts x 32 ch; thread t handles 4 elems (interleaved row)
    int pt = tid >> 3, c0 = (tid & 7) * 4;
    size_t g = (size_t)(blockIdx.x * 32 + pt) * 64 + c0;
    bf16x4 rh = *(const bf16x4*)(f + g);
    bf16x4 rl = *(const bf16x4*)(f + g + 32);
    bf16x4 oh4, ol4;
    if (MODE == 0){
        #pragma unroll
        for (int j = 0; j < 4; j++){
            float v = buf0[pt][c0 + j] + (float)rh[j] + (float)rl[j];
            __bf16 hi = (__bf16)v;
            oh4[j] = hi;
            ol4[j] = (__bf16)(v - (float)hi);
        }
    } else {
        bf16x4 sh = *(const bf16x4*)(r2 + g);
        bf16x4 sl = *(const bf16x4*)(r2 + g + 32);
        #pragma unroll
        for (int j = 0; j < 4; j++){
            float v = buf0[pt][c0 + j] + (float)rh[j] + (float)rl[j]
                                       + (float)sh[j] + (float)sl[j];
            __bf16 hi = (__bf16)v;
            oh4[j] = hi;
            ol4[j] = (__bf16)(v - (float)hi);
        }
    }
    *(bf16x4*)(outp + g)      = oh4;
    *(bf16x4*)(outp + g + 32) = ol4;
}

// mlp2: out[m,128] = b2 + sum_kc v_kc[m,32] @ w2[kc] (3-term hi/lo MFMA).
// Wave owns 32 distinct points x all 4 out-slices + 2-stage kc prefetch.
// Interleaved v planes (stride 8,388,608 elems/plane).
__global__ __launch_bounds__(256)
void mlp2_kernel(const __bf16* __restrict__ vplanes,
                 const __bf16* __restrict__ w2th, const __bf16* __restrict__ w2tl,
                 const float* __restrict__ b2, float* __restrict__ out)
{
    int tid  = threadIdx.x;
    int lane = tid & 63, w = tid >> 6;
    int col  = lane & 15, kq = lane >> 4;
    const int fragoff = kq * 8;
    int pbase = blockIdx.x * 128 + w * 32;
    size_t oA = (size_t)(pbase + col) * 64 + fragoff;
    size_t oB = (size_t)(pbase + 16 + col) * 64 + fragoff;

    f32x4 acc[4][4];
    #pragma unroll
    for (int s = 0; s < 4; s++)
        #pragma unroll
        for (int q = 0; q < 4; q++) acc[s][q] = (f32x4){0,0,0,0};

    bf16x8 a0h = *(const bf16x8*)(vplanes + oA);
    bf16x8 a0l = *(const bf16x8*)(vplanes + oA + 32);
    bf16x8 a1h = *(const bf16x8*)(vplanes + oB);
    bf16x8 a1l = *(const bf16x8*)(vplanes + oB + 32);

    #pragma unroll 1
    for (int kc = 0; kc < 8; kc++){
        bf16x8 na0h, na0l, na1h, na1l;
        if (kc < 7){
            const __bf16* fn = vplanes + (size_t)(kc+1) * 8388608;
            na0h = *(const bf16x8*)(fn + oA);
            na0l = *(const bf16x8*)(fn + oA + 32);
            na1h = *(const bf16x8*)(fn + oB);
            na1l = *(const bf16x8*)(fn + oB + 32);
        } else {
            na0h = a0h; na0l = a0l; na1h = a1h; na1l = a1l;
        }

        const __bf16* wbase  = w2th + (size_t)kc * 4096;
        const __bf16* wlbase = w2tl + (size_t)kc * 4096;
        #pragma unroll
        for (int s = 0; s < 4; s++){
            const __bf16* wb = wbase  + (s*32 + col) * 32 + fragoff;
            const __bf16* wc = wlbase + (s*32 + col) * 32 + fragoff;
            bf16x8 b0h = *(const bf16x8*)(wb);
            bf16x8 b1h = *(const bf16x8*)(wb + 512);
            bf16x8 b0l = *(const bf16x8*)(wc);
            bf16x8 b1l = *(const bf16x8*)(wc + 512);

            acc[s][0] = __builtin_amdgcn_mfma_f32_16x16x32_bf16(a0h, b0h, acc[s][0], 0,0,0);
            acc[s][0] = __builtin_amdgcn_mfma_f32_16x16x32_bf16(a0h, b0l, acc[s][0], 0,0,0);
            acc[s][0] = __builtin_amdgcn_mfma_f32_16x16x32_bf16(a0l, b0h, acc[s][0], 0,0,0);
            acc[s][1] = __builtin_amdgcn_mfma_f32_16x16x32_bf16(a0h, b1h, acc[s][1], 0,0,0);
            acc[s][1] = __builtin_amdgcn_mfma_f32_16x16x32_bf16(a0h, b1l, acc[s][1], 0,0,0);
            acc[s][1] = __builtin_amdgcn_mfma_f32_16x16x32_bf16(a0l, b1h, acc[s][1], 0,0,0);
            acc[s][2] = __builtin_amdgcn_mfma_f32_16x16x32_bf16(a1h, b0h, acc[s][2], 0,0,0);
            acc[s][2] = __builtin_amdgcn_mfma_f32_16x16x32_bf16(a1h, b0l, acc[s][2], 0,0,0);
            acc[s][2] = __builtin_amdgcn_mfma_f32_16x16x32_bf16(a1l, b0h, acc[s][2], 0,0,0);
            acc[s][3] = __builtin_amdgcn_mfma_f32_16x16x32_bf16(a1h, b1h, acc[s][3], 0,0,0);
            acc[s][3] = __builtin_amdgcn_mfma_f32_16x16x32_bf16(a1h, b1l, acc[s][3], 0,0,0);
            acc[s][3] = __builtin_amdgcn_mfma_f32_16x16x32_bf16(a1l, b1h, acc[s][3], 0,0,0);
        }

        a0h = na0h; a0l = na0l; a1h = na1h; a1l = na1l;
    }

    #pragma unroll
    for (int s = 0; s < 4; s++){
        float bl = b2[s*32 + col], bh = b2[s*32 + 16 + col];
        #pragma unroll
        for (int r = 0; r < 4; r++){
            size_t rowA = (size_t)(pbase + kq*4 + r) * 128;
            size_t rowB = (size_t)(pbase + 16 + kq*4 + r) * 128;
            out[rowA + s*32 + col]      = acc[s][0][r] + bl;
            out[rowA + s*32 + 16 + col] = acc[s][1][r] + bh;
            out[rowB + s*32 + col]      = acc[s][2][r] + bl;
            out[rowB + s*32 + 16 + col] = acc[s][3][r] + bh;
        }
    }
}

// ================================================================ FALLBACK PATH (round-9 split-plane, verbatim)
template<int MODE>
__global__ __launch_bounds__(256)
void conv_mfma_kernel(const __bf16* __restrict__ fh, const __bf16* __restrict__ fl,
                      const __bf16* __restrict__ wth, const __bf16* __restrict__ wtl,
                      const float* __restrict__ bias, const int* __restrict__ nbr,
                      const __bf16* __restrict__ r2h, const __bf16* __restrict__ r2l,
                      const float* __restrict__ w2i, const float* __restrict__ b2,
                      __bf16* __restrict__ outh, __bf16* __restrict__ outl,
                      float* __restrict__ out)
{
    __shared__ float vsh[64][33];
    int tid  = threadIdx.x;
    int lane = tid & 63, wid = tid >> 6;
    int pair = wid >> 1;
    int half = wid & 1;
    int col  = lane & 15, kq = lane >> 4;
    int m0   = blockIdx.x * 64 + pair * 32;
    int ptA  = m0 + col, ptB = ptA + 16;
    const int fragoff = kq * 8;

    f32x4 acc00, acc01, acc10, acc11;
    if (half == 0){
        float bv0 = bias[col], bv1 = bias[col + 16];
        acc00 = (f32x4){bv0,bv0,bv0,bv0}; acc01 = (f32x4){bv1,bv1,bv1,bv1};
        acc10 = (f32x4){bv0,bv0,bv0,bv0}; acc11 = (f32x4){bv1,bv1,bv1,bv1};
    } else {
        acc00 = (f32x4){0,0,0,0}; acc01 = (f32x4){0,0,0,0};
        acc10 = (f32x4){0,0,0,0}; acc11 = (f32x4){0,0,0,0};
    }

    int k0 = half ? 14 : 0;
    int k1 = half ? 27 : 14;
    #pragma unroll 1
    for (int k = k0; k < k1; k++){
        int nb0 = nbr[k * MTOT + ptA];
        int nb1 = nbr[k * MTOT + ptB];
        size_t o0 = (size_t)(nb0 < 0 ? 0 : nb0) * 32 + fragoff;
        size_t o1 = (size_t)(nb1 < 0 ? 0 : nb1) * 32 + fragoff;
        bf16x8 a0h = *(const bf16x8*)(fh + o0);
        bf16x8 a0l = *(const bf16x8*)(fl + o0);
        bf16x8 a1h = *(const bf16x8*)(fh + o1);
        bf16x8 a1l = *(const bf16x8*)(fl + o1);
        bf16x8 z = {};
        if (nb0 < 0){ a0h = z; a0l = z; }
        if (nb1 < 0){ a1h = z; a1l = z; }

        const __bf16* wb = wth + (size_t)k*1024 + col*32 + fragoff;
        const __bf16* wc = wtl + (size_t)k*1024 + col*32 + fragoff;
        bf16x8 b0h = *(const bf16x8*)(wb);
        bf16x8 b1h = *(const bf16x8*)(wb + 512);
        bf16x8 b0l = *(const bf16x8*)(wc);
        bf16x8 b1l = *(const bf16x8*)(wc + 512);

        acc00 = __builtin_amdgcn_mfma_f32_16x16x32_bf16(a0h, b0h, acc00, 0,0,0);
        acc00 = __builtin_amdgcn_mfma_f32_16x16x32_bf16(a0h, b0l, acc00, 0,0,0);
        acc00 = __builtin_amdgcn_mfma_f32_16x16x32_bf16(a0l, b0h, acc00, 0,0,0);
        acc01 = __builtin_amdgcn_mfma_f32_16x16x32_bf16(a0h, b1h, acc01, 0,0,0);
        acc01 = __builtin_amdgcn_mfma_f32_16x16x32_bf16(a0h, b1l, acc01, 0,0,0);
        acc01 = __builtin_amdgcn_mfma_f32_16x16x32_bf16(a0l, b1h, acc01, 0,0,0);
        acc10 = __builtin_amdgcn_mfma_f32_16x16x32_bf16(a1h, b0h, acc10, 0,0,0);
        acc10 = __builtin_amdgcn_mfma_f32_16x16x32_bf16(a1h, b0l, acc10, 0,0,0);
        acc10 = __builtin_amdgcn_mfma_f32_16x16x32_bf16(a1l, b0h, acc10, 0,0,0);
        acc11 = __builtin_amdgcn_mfma_f32_16x16x32_bf16(a1h, b1h, acc11, 0,0,0);
        acc11 = __builtin_amdgcn_mfma_f32_16x16x32_bf16(a1h, b1l, acc11, 0,0,0);
        acc11 = __builtin_amdgcn_mfma_f32_16x16x32_bf16(a1l, b1h, acc11, 0,0,0);
    }

    if (half == 1){
        #pragma unroll
        for (int r = 0; r < 4; r++){
            vsh[pair*32 + kq*4 + r][col]           = acc00[r];
            vsh[pair*32 + kq*4 + r][col + 16]      = acc01[r];
            vsh[pair*32 + 16 + kq*4 + r][col]      = acc10[r];
            vsh[pair*32 + 16 + kq*4 + r][col + 16] = acc11[r];
        }
    }
    __syncthreads();
    if (half == 0){
        #pragma unroll
        for (int r = 0; r < 4; r++){
            vsh[pair*32 + kq*4 + r][col]           += acc00[r];
            vsh[pair*32 + kq*4 + r][col + 16]      += acc01[r];
            vsh[pair*32 + 16 + kq*4 + r][col]      += acc10[r];
            vsh[pair*32 + 16 + kq*4 + r][col + 16] += acc11[r];
        }
    }
    __syncthreads();

    if (MODE == 0){
        int eidx = tid * 8;
        int pt = eidx >> 5, c0 = eidx & 31;
        size_t g = (size_t)blockIdx.x * 2048 + eidx;
        bf16x8 rh = *(const bf16x8*)(fh + g);
        bf16x8 rl = *(const bf16x8*)(fl + g);
        bf16x8 oh8, ol8;
        #pragma unroll
        for (int j = 0; j < 8; j++){
            float v = vsh[pt][c0 + j] + (float)rh[j] + (float)rl[j];
            __bf16 hi = (__bf16)v;
            oh8[j] = hi;
            ol8[j] = (__bf16)(v - (float)hi);
        }
        *(bf16x8*)(outh + g) = oh8;
        *(bf16x8*)(outl + g) = ol8;
    } else {
        int eidx = tid * 8;
        int pt = eidx >> 5, c0 = eidx & 31;
        size_t g = (size_t)blockIdx.x * 2048 + eidx;
        bf16x8 rh = *(const bf16x8*)(fh + g);
        bf16x8 rl = *(const bf16x8*)(fl + g);
        bf16x8 sh = *(const bf16x8*)(r2h + g);
        bf16x8 sl = *(const bf16x8*)(r2l + g);
        #pragma unroll
        for (int j = 0; j < 8; j++)
            vsh[pt][c0 + j] += (float)rh[j] + (float)rl[j] + (float)sh[j] + (float)sl[j];
        __syncthreads();

        int pm = tid & 63;
        int tg = __builtin_amdgcn_readfirstlane(tid >> 6);
        size_t m = (size_t)blockIdx.x * 64 + pm;
        float o32[32];
        float* obase = out + m*128 + tg*32;
        if (MODE == 2){
            #pragma unroll
            for (int o = 0; o < 32; o++) o32[o] = b2[tg*32 + o];
        } else {
            #pragma unroll
            for (int q = 0; q < 8; q++){
                float4 t4 = ((const float4*)obase)[q];
                o32[q*4+0] = t4.x; o32[q*4+1] = t4.y; o32[q*4+2] = t4.z; o32[q*4+3] = t4.w;
            }
        }
        #pragma unroll
        for (int c = 0; c < 32; c++){
            float vc = vsh[pm][c];
            const float* w2r = w2i + c*128 + tg*32;
            #pragma unroll
            for (int o = 0; o < 32; o++) o32[o] += vc * w2r[o];
        }
        #pragma unroll
        for (int q = 0; q < 8; q++)
            ((float4*)obase)[q] = make_float4(o32[q*4+0], o32[q*4+1], o32[q*4+2], o32[q*4+3]);
    }
}

// ---------------------------------------------------------------- launch
extern "C" void kernel_launch(void* const* d_in, const int* in_sizes, int n_in,
                              void* d_out, int out_size, void* d_ws, size_t ws_size,
                              hipStream_t stream)
{
    static const int want[9] = {393216, 96, 32, 8192, 256, 442368, 512, 32768, 128};
    const void* bound[9];
    for (int i = 0; i < 9; i++) bound[i] = d_in[i];
    if (n_in == 9){
        for (int i = 0; i < 9; i++)
            for (int j = 0; j < 9; j++)
                if (in_sizes[j] == want[i]) { bound[i] = d_in[j]; break; }
    }
    const float* p      = (const float*)bound[0];
    const float* w1     = (const float*)bound[1];
    const float* b1     = (const float*)bound[2];
    const float* w_mlp  = (const float*)bound[3];
    const float* b_mlp  = (const float*)bound[4];
    const float* w_conv = (const float*)bound[5];
    const float* b_conv = (const float*)bound[6];
    const float* w2     = (const float*)bound[7];
    const float* b2     = (const float*)bound[8];
    float* out = (float*)d_out;

    char* ws = (char*)d_ws;
    // ---- big-path layout (interleaved planes, MTOT+1 rows each) ----
    __bf16* h0i  = (__bf16*)(ws);                        // 16,777,344 B used
    __bf16* h1i  = (__bf16*)(ws + 16842752);             // 0x1010000
    int*    vg_b = (int*)   (ws + 16842752);             // alias (8,242,408 B)
    int*    gc_b = (int*)   (ws + 16842752 + 8388608);   // alias (524,288 B)
    int*    nbr  = (int*)   (ws + 33685504);             // 0x2020000, 14,155,776 B
    __bf16* wth  = (__bf16*)(ws + 47841280);             // 884,736 B
    __bf16* wtl  = (__bf16*)(ws + 48726016);             // 884,736 B
    __bf16* w2th = (__bf16*)(ws + 49610752);             // 65,536 B
    __bf16* w2tl = (__bf16*)(ws + 49676288);             // 65,536 B
    float*  pmin = (float*) (ws + 49741824);
    __bf16* vpl  = (__bf16*)(ws + 50331648);             // 8 x 16 MiB v planes

    // ---- fallback layout (split planes, r9-style) ----
    __bf16* h0h  = (__bf16*)(ws);
    __bf16* h0l  = (__bf16*)(ws + 8388608);
    __bf16* h1h  = (__bf16*)(ws + 16777216);
    int*    vg_f = (int*)   (ws + 16777216);             // alias of h1h
    __bf16* h1l  = (__bf16*)(ws + 25165824);
    int*    gc_f = (int*)   (ws + 25165824);             // alias of h1l

    const bool big = (ws_size >= 184549376ULL);
    int* vgrid = big ? vg_b : vg_f;
    int* gcbuf = big ? gc_b : gc_f;

    static const double GS[8] = {0.01, 0.02, 0.04, 0.08, 0.16, 0.32, 0.64, 1.28};
    static const int    DS[8] = {101, 51, 26, 14, 8, 5, 3, 2};   // ceil(1/g)+1

    pmin_init_kernel<<<1, 64, 0, stream>>>(pmin);
    pmin_kernel<<<dim3(64, 2), 256, 0, stream>>>(p, pmin);
    wcv_kernel<<<1728, 256, 0, stream>>>(w_conv, wth, wtl);
    if (big){
        w2t_kernel<<<128, 256, 0, stream>>>(w2, w2th, w2tl);
        zero_rows_kernel<<<1, 128, 0, stream>>>(h0i, h1i);
    }

    for (int i = 0; i < 8; i++){
        int D = DS[i]; double gd = GS[i];
        int ncell = D * D * D;
        hipMemsetAsync(vgrid, 0xFF, (size_t)2*ncell*sizeof(int), stream);
        if (ncell <= 2744)
            scatter_kernel<1><<<MTOT/256, 256, ncell*sizeof(int), stream>>>(p, pmin, vgrid, gcbuf, gd, D);
        else
            scatter_kernel<0><<<MTOT/256, 256, 0, stream>>>(p, pmin, vgrid, gcbuf, gd, D);
        nbr_kernel<<<MTOT/256, 256, 0, stream>>>(gcbuf, vgrid, nbr, D);

        if (big){
            mlp_scale_i_kernel<<<(MTOT*32)/256, 256, 0, stream>>>(
                p, w1, b1, w_mlp + i*1024, b_mlp + i*32, h0i);
            conv4_kernel<0><<<MTOT/32, 256, 0, stream>>>(
                h0i, wth + (size_t)(2*i)*27648, wtl + (size_t)(2*i)*27648,
                b_conv + (2*i)*32, nbr, nullptr, h1i);
            conv4_kernel<1><<<MTOT/32, 256, 0, stream>>>(
                h1i, wth + (size_t)(2*i+1)*27648, wtl + (size_t)(2*i+1)*27648,
                b_conv + (2*i+1)*32, nbr, h0i, vpl + (size_t)i*8388608);
        } else {
            mlp_scale_s_kernel<<<(MTOT*32)/256, 256, 0, stream>>>(
                p, w1, b1, w_mlp + i*1024, b_mlp + i*32, h0h, h0l);
            conv_mfma_kernel<0><<<MTOT/64, 256, 0, stream>>>(
                h0h, h0l, wth + (size_t)(2*i)*27648, wtl + (size_t)(2*i)*27648,
                b_conv + (2*i)*32, nbr, nullptr, nullptr, nullptr, nullptr,
                h1h, h1l, nullptr);
            if (i == 0)
                conv_mfma_kernel<2><<<MTOT/64, 256, 0, stream>>>(
                    h1h, h1l, wth + (size_t)(2*i+1)*27648, wtl + (size_t)(2*i+1)*27648,
                    b_conv + (2*i+1)*32, nbr, h0h, h0l, w2 + i*32*128, b2,
                    nullptr, nullptr, out);
            else
                conv_mfma_kernel<1><<<MTOT/64, 256, 0, stream>>>(
                    h1h, h1l, wth + (size_t)(2*i+1)*27648, wtl + (size_t)(2*i+1)*27648,
                    b_conv + (2*i+1)*32, nbr, h0h, h0l, w2 + i*32*128, nullptr,
                    nullptr, nullptr, out);
        }
    }
    if (big)
        mlp2_kernel<<<MTOT/128, 256, 0, stream>>>(vpl, w2th, w2tl, b2, out);
}

// Round 13
// 1213.197 us; speedup vs baseline: 1.2126x; 1.2126x over previous
//
#include <hip/hip_runtime.h>

#define MTOT 131072   // b*n
#define NB   65536    // n per batch

typedef __attribute__((ext_vector_type(8))) __bf16 bf16x8;
typedef __attribute__((ext_vector_type(4))) __bf16 bf16x4;
typedef __attribute__((ext_vector_type(4))) float  f32x4;

// ---------------------------------------------------------------- pmin
__global__ void pmin_init_kernel(float* pmin){
    if (threadIdx.x < 6) pmin[threadIdx.x] = 2.0f;   // p in [0,1)
}

__global__ void pmin_kernel(const float* __restrict__ p, float* __restrict__ pmin){
    int bi = blockIdx.y;
    float m0 = 2.f, m1 = 2.f, m2 = 2.f;
    for (int ni = blockIdx.x * blockDim.x + threadIdx.x; ni < NB; ni += gridDim.x * blockDim.x){
        const float* pp = p + ((size_t)bi * NB + ni) * 3;
        m0 = fminf(m0, pp[0]); m1 = fminf(m1, pp[1]); m2 = fminf(m2, pp[2]);
    }
    #pragma unroll
    for (int o = 32; o > 0; o >>= 1){
        m0 = fminf(m0, __shfl_down(m0, o, 64));
        m1 = fminf(m1, __shfl_down(m1, o, 64));
        m2 = fminf(m2, __shfl_down(m2, o, 64));
    }
    if ((threadIdx.x & 63) == 0){
        atomicMin((int*)(pmin + bi*3 + 0), __float_as_int(m0));
        atomicMin((int*)(pmin + bi*3 + 1), __float_as_int(m1));
        atomicMin((int*)(pmin + bi*3 + 2), __float_as_int(m2));
    }
}

// ---------------------------------------------------------------- voxel scatter (atomicMax of ids)
// f64 voxelization (floor(p/g) in double) matches the numpy f64 reference bit-exactly.
template<int USE_LDS>
__global__ void scatter_kernel(const float* __restrict__ p, const float* __restrict__ pmin,
                               int* __restrict__ vgrid, int* __restrict__ gcbuf,
                               double gd, int D){
    extern __shared__ int lgrid[];
    int m  = blockIdx.x * blockDim.x + threadIdx.x;
    int bi = m >> 16;
    double px = (double)p[m*3], py = (double)p[m*3+1], pz = (double)p[m*3+2];
    int gx = (int)floor(px / gd) - (int)floor((double)pmin[bi*3+0] / gd);
    int gy = (int)floor(py / gd) - (int)floor((double)pmin[bi*3+1] / gd);
    int gz = (int)floor(pz / gd) - (int)floor((double)pmin[bi*3+2] / gd);
    gcbuf[m] = (gx << 20) | (gy << 10) | gz;
    int cell = (gx * D + gy) * D + gz;

    if (!USE_LDS){
        atomicMax(vgrid + bi * D * D * D + cell, m);
        return;
    }
    int ncell = D * D * D;
    for (int c = threadIdx.x; c < ncell; c += 256) lgrid[c] = -1;
    __syncthreads();
    atomicMax(&lgrid[cell], m);
    __syncthreads();
    int* vg = vgrid + bi * ncell;
    for (int c = threadIdx.x; c < ncell; c += 256){
        int v = lgrid[c];
        if (v >= 0) atomicMax(vg + c, v);
    }
}

// ---------------------------------------------------------------- 27-tap neighbor table
__global__ void nbr_kernel(const int* __restrict__ gcbuf, const int* __restrict__ vgrid,
                           int* __restrict__ nbr, int D){
    int m  = blockIdx.x * blockDim.x + threadIdx.x;
    int bi = m >> 16;
    int pk = gcbuf[m];
    int gx = pk >> 20, gy = (pk >> 10) & 1023, gz = pk & 1023;
    #pragma unroll
    for (int k = 0; k < 27; k++){
        int v;
        if (k == 13){
            v = m;
        } else {
            int x = gx + (k/9) - 1;
            int y = gy + ((k/3)%3) - 1;
            int z = gz + (k%3) - 1;
            if (x < 0 || y < 0 || z < 0 || x >= D || y >= D || z >= D) v = -1;
            else v = vgrid[((bi * D + x) * D + y) * D + z];
        }
        nbr[k * MTOT + m] = v;
    }
}

// ---------------------------------------------------------------- W_conv -> WAVE-LINEAR bf16 hi/lo planes (big path)
// wt2[cv][k][half][l][e] = W[cv][k][ j=(l>>4)*8+e ][ c=half*16+(l&15) ]
// -> a wave's B-fragment load is one contiguous 1-KB burst (lane l reads 16 B at
//    base + l*16) instead of 16 scattered 64-B lines. Bitwise-identical MFMA inputs.
__global__ void wcv_wave_kernel(const float* __restrict__ w_conv,
                                __bf16* __restrict__ wth, __bf16* __restrict__ wtl){
    int o = blockIdx.x * 256 + threadIdx.x;          // 442368 total
    int cv = o / 27648, r = o % 27648;
    int k = r / 1024, q = r % 1024;
    int half = q >> 9, t = q & 511;
    int l = t >> 3, e = t & 7;
    int c = half*16 + (l & 15);
    int j = (l >> 4)*8 + e;
    float x = w_conv[cv*27648 + k*1024 + j*32 + c];
    __bf16 hi = (__bf16)x;
    wth[o] = hi;
    wtl[o] = (__bf16)(x - (float)hi);
}

// ---------------------------------------------------------------- W_conv -> [k][c][j] layout (fallback path)
__global__ void wcv_kernel(const float* __restrict__ w_conv,
                           __bf16* __restrict__ wth, __bf16* __restrict__ wtl){
    int o = blockIdx.x * 256 + threadIdx.x;          // 442368 total
    int cv = o / 27648, r = o % 27648;
    int k = r / 1024, q = r % 1024, c = q / 32, j = q % 32;
    float x = w_conv[cv*27648 + k*1024 + j*32 + c];
    __bf16 hi = (__bf16)x;
    wth[o] = hi;
    wtl[o] = (__bf16)(x - (float)hi);
}

// ---------------------------------------------------------------- w2 -> [kc][c(128)][j(32)] bf16 hi/lo
__global__ void w2t_kernel(const float* __restrict__ w2,
                           __bf16* __restrict__ w2th, __bf16* __restrict__ w2tl){
    int o = blockIdx.x * 256 + threadIdx.x;          // 32768 total
    int kc = o >> 12, r = o & 4095, c = r >> 5, j = r & 31;
    float x = w2[(kc*32 + j)*128 + c];
    __bf16 hi = (__bf16)x;
    w2th[o] = hi;
    w2tl[o] = (__bf16)(x - (float)hi);
}

// ---------------------------------------------------------------- fused mlp1 + per-scale mlp -> bf16 hi/lo planes
__global__ void mlp_scale_kernel(const float* __restrict__ p, const float* __restrict__ w1,
                                 const float* __restrict__ b1,
                                 const float* __restrict__ w, const float* __restrict__ b,
                                 __bf16* __restrict__ h0h, __bf16* __restrict__ h0l){
    int t = blockIdx.x * blockDim.x + threadIdx.x;
    int c = t & 31, m = t >> 5;
    float x = p[m*3+0], y = p[m*3+1], z = p[m*3+2];
    float acc = b[c];
    #pragma unroll
    for (int j = 0; j < 32; j++){
        float ptsj = b1[j] + x * w1[j] + y * w1[32 + j] + z * w1[64 + j];
        acc += ptsj * w[j*32 + c];
    }
    __bf16 hi = (__bf16)acc;
    h0h[t] = hi;
    h0l[t] = (__bf16)(acc - (float)hi);
}

// ================================================================ BIG-WS PATH (r11 structure + wave-linear W)
// conv4: 4-way tap split + 2-stage pipeline. W-loads use the wave-linear layout.
// MODE 0: h1 planes = conv(f) + f
// MODE 1: v planes  = conv(f) + f + h0      (w2 GEMM deferred to mlp2_kernel)
template<int MODE>
__global__ __launch_bounds__(256)
void conv4_kernel(const __bf16* __restrict__ fh, const __bf16* __restrict__ fl,
                  const __bf16* __restrict__ wth, const __bf16* __restrict__ wtl,
                  const float* __restrict__ bias, const int* __restrict__ nbr,
                  const __bf16* __restrict__ r2h, const __bf16* __restrict__ r2l,
                  __bf16* __restrict__ outh, __bf16* __restrict__ outl)
{
    __shared__ float buf0[32][33], buf1[32][33];
    int tid  = threadIdx.x;
    int lane = tid & 63, w = tid >> 6;
    int col  = lane & 15, kq = lane >> 4;
    int ptA  = blockIdx.x * 32 + col, ptB = ptA + 16;
    const int fragoff = kq * 8;

    f32x4 acc00, acc01, acc10, acc11;
    if (w == 0){
        float bv0 = bias[col], bv1 = bias[col + 16];
        acc00 = (f32x4){bv0,bv0,bv0,bv0}; acc01 = (f32x4){bv1,bv1,bv1,bv1};
        acc10 = (f32x4){bv0,bv0,bv0,bv0}; acc11 = (f32x4){bv1,bv1,bv1,bv1};
    } else {
        acc00 = (f32x4){0,0,0,0}; acc01 = (f32x4){0,0,0,0};
        acc10 = (f32x4){0,0,0,0}; acc11 = (f32x4){0,0,0,0};
    }

    int k0 = w * 7, k1 = (k0 + 7 < 27) ? k0 + 7 : 27;

    // pipeline prologue: rows for k0 + ids for k0+1
    int idc = nbr[k0 * MTOT + ptA];
    int jdc = nbr[k0 * MTOT + ptB];
    int idn = (k0 + 1 < k1) ? nbr[(k0+1) * MTOT + ptA] : 0;
    int jdn = (k0 + 1 < k1) ? nbr[(k0+1) * MTOT + ptB] : 0;
    size_t oc0 = (size_t)(idc < 0 ? 0 : idc) * 32 + fragoff;
    size_t oc1 = (size_t)(jdc < 0 ? 0 : jdc) * 32 + fragoff;
    bf16x8 a0h = *(const bf16x8*)(fh + oc0);
    bf16x8 a0l = *(const bf16x8*)(fl + oc0);
    bf16x8 a1h = *(const bf16x8*)(fh + oc1);
    bf16x8 a1l = *(const bf16x8*)(fl + oc1);
    bool mc0 = idc < 0, mc1 = jdc < 0;

    #pragma unroll 1
    for (int k = k0; k < k1; k++){
        int idn2 = 0, jdn2 = 0;
        if (k + 2 < k1){ idn2 = nbr[(k+2) * MTOT + ptA]; jdn2 = nbr[(k+2) * MTOT + ptB]; }
        size_t on0 = (size_t)(idn < 0 ? 0 : idn) * 32 + fragoff;
        size_t on1 = (size_t)(jdn < 0 ? 0 : jdn) * 32 + fragoff;
        bf16x8 na0h = *(const bf16x8*)(fh + on0);
        bf16x8 na0l = *(const bf16x8*)(fl + on0);
        bf16x8 na1h = *(const bf16x8*)(fh + on1);
        bf16x8 na1l = *(const bf16x8*)(fl + on1);
        bool nm0 = idn < 0, nm1 = jdn < 0;

        // wave-linear W: lane reads its 16 B at base + lane*8 elems (contiguous 1 KB)
        const __bf16* wb = wth + (size_t)k*1024 + lane*8;
        const __bf16* wc = wtl + (size_t)k*1024 + lane*8;
        bf16x8 b0h = *(const bf16x8*)(wb);
        bf16x8 b1h = *(const bf16x8*)(wb + 512);
        bf16x8 b0l = *(const bf16x8*)(wc);
        bf16x8 b1l = *(const bf16x8*)(wc + 512);

        bf16x8 z = {};
        bf16x8 xa0h = mc0 ? z : a0h, xa0l = mc0 ? z : a0l;
        bf16x8 xa1h = mc1 ? z : a1h, xa1l = mc1 ? z : a1l;

        acc00 = __builtin_amdgcn_mfma_f32_16x16x32_bf16(xa0h, b0h, acc00, 0,0,0);
        acc00 = __builtin_amdgcn_mfma_f32_16x16x32_bf16(xa0h, b0l, acc00, 0,0,0);
        acc00 = __builtin_amdgcn_mfma_f32_16x16x32_bf16(xa0l, b0h, acc00, 0,0,0);
        acc01 = __builtin_amdgcn_mfma_f32_16x16x32_bf16(xa0h, b1h, acc01, 0,0,0);
        acc01 = __builtin_amdgcn_mfma_f32_16x16x32_bf16(xa0h, b1l, acc01, 0,0,0);
        acc01 = __builtin_amdgcn_mfma_f32_16x16x32_bf16(xa0l, b1h, acc01, 0,0,0);
        acc10 = __builtin_amdgcn_mfma_f32_16x16x32_bf16(xa1h, b0h, acc10, 0,0,0);
        acc10 = __builtin_amdgcn_mfma_f32_16x16x32_bf16(xa1h, b0l, acc10, 0,0,0);
        acc10 = __builtin_amdgcn_mfma_f32_16x16x32_bf16(xa1l, b0h, acc10, 0,0,0);
        acc11 = __builtin_amdgcn_mfma_f32_16x16x32_bf16(xa1h, b1h, acc11, 0,0,0);
        acc11 = __builtin_amdgcn_mfma_f32_16x16x32_bf16(xa1h, b1l, acc11, 0,0,0);
        acc11 = __builtin_amdgcn_mfma_f32_16x16x32_bf16(xa1l, b1h, acc11, 0,0,0);

        a0h = na0h; a0l = na0l; a1h = na1h; a1l = na1l;
        mc0 = nm0; mc1 = nm1; idn = idn2; jdn = jdn2;
    }

    // tree combine: final = (bias+T0+T2) + (T1+T3)
    if (w == 2){
        #pragma unroll
        for (int r = 0; r < 4; r++){
            buf0[kq*4 + r][col]           = acc00[r];
            buf0[kq*4 + r][col + 16]      = acc01[r];
            buf0[16 + kq*4 + r][col]      = acc10[r];
            buf0[16 + kq*4 + r][col + 16] = acc11[r];
        }
    } else if (w == 3){
        #pragma unroll
        for (int r = 0; r < 4; r++){
            buf1[kq*4 + r][col]           = acc00[r];
            buf1[kq*4 + r][col + 16]      = acc01[r];
            buf1[16 + kq*4 + r][col]      = acc10[r];
            buf1[16 + kq*4 + r][col + 16] = acc11[r];
        }
    }
    __syncthreads();
    if (w == 0){
        #pragma unroll
        for (int r = 0; r < 4; r++){
            acc00[r] += buf0[kq*4 + r][col];
            acc01[r] += buf0[kq*4 + r][col + 16];
            acc10[r] += buf0[16 + kq*4 + r][col];
            acc11[r] += buf0[16 + kq*4 + r][col + 16];
        }
    } else if (w == 1){
        #pragma unroll
        for (int r = 0; r < 4; r++){
            acc00[r] += buf1[kq*4 + r][col];
            acc01[r] += buf1[kq*4 + r][col + 16];
            acc10[r] += buf1[16 + kq*4 + r][col];
            acc11[r] += buf1[16 + kq*4 + r][col + 16];
        }
    }
    __syncthreads();
    if (w == 1){
        #pragma unroll
        for (int r = 0; r < 4; r++){
            buf1[kq*4 + r][col]           = acc00[r];
            buf1[kq*4 + r][col + 16]      = acc01[r];
            buf1[16 + kq*4 + r][col]      = acc10[r];
            buf1[16 + kq*4 + r][col + 16] = acc11[r];
        }
    }
    __syncthreads();
    if (w == 0){
        #pragma unroll
        for (int r = 0; r < 4; r++){
            buf0[kq*4 + r][col]           = acc00[r] + buf1[kq*4 + r][col];
            buf0[kq*4 + r][col + 16]      = acc01[r] + buf1[kq*4 + r][col + 16];
            buf0[16 + kq*4 + r][col]      = acc10[r] + buf1[16 + kq*4 + r][col];
            buf0[16 + kq*4 + r][col + 16] = acc11[r] + buf1[16 + kq*4 + r][col + 16];
        }
    }
    __syncthreads();

    // epilogue: 32 pts x 32 ch; thread t handles 4 elems
    int pt = tid >> 3, c0 = (tid & 7) * 4;
    size_t g = (size_t)(blockIdx.x * 32 + pt) * 32 + c0;
    bf16x4 rh = *(const bf16x4*)(fh + g);
    bf16x4 rl = *(const bf16x4*)(fl + g);
    bf16x4 oh4, ol4;
    if (MODE == 0){
        #pragma unroll
        for (int j = 0; j < 4; j++){
            float v = buf0[pt][c0 + j] + (float)rh[j] + (float)rl[j];
            __bf16 hi = (__bf16)v;
            oh4[j] = hi;
            ol4[j] = (__bf16)(v - (float)hi);
        }
    } else {
        bf16x4 sh = *(const bf16x4*)(r2h + g);
        bf16x4 sl = *(const bf16x4*)(r2l + g);
        #pragma unroll
        for (int j = 0; j < 4; j++){
            float v = buf0[pt][c0 + j] + (float)rh[j] + (float)rl[j]
                                       + (float)sh[j] + (float)sl[j];
            __bf16 hi = (__bf16)v;
            oh4[j] = hi;
            ol4[j] = (__bf16)(v - (float)hi);
        }
    }
    *(bf16x4*)(outh + g) = oh4;
    *(bf16x4*)(outl + g) = ol4;
}

// mlp2: out[m,128] = b2 + sum_kc v_kc[m,32] @ w2[kc] (3-term hi/lo MFMA).
// Wave owns 32 distinct points x all 4 out-slices + 2-stage kc prefetch of A.
__global__ __launch_bounds__(256)
void mlp2_kernel(const __bf16* __restrict__ vplanes,
                 const __bf16* __restrict__ w2th, const __bf16* __restrict__ w2tl,
                 const float* __restrict__ b2, float* __restrict__ out)
{
    int tid  = threadIdx.x;
    int lane = tid & 63, w = tid >> 6;
    int col  = lane & 15, kq = lane >> 4;
    const int fragoff = kq * 8;
    int pbase = blockIdx.x * 128 + w * 32;
    size_t oA = (size_t)(pbase + col) * 32 + fragoff;
    size_t oB = (size_t)(pbase + 16 + col) * 32 + fragoff;

    f32x4 acc[4][4];
    #pragma unroll
    for (int s = 0; s < 4; s++)
        #pragma unroll
        for (int q = 0; q < 4; q++) acc[s][q] = (f32x4){0,0,0,0};

    bf16x8 a0h = *(const bf16x8*)(vplanes + oA);
    bf16x8 a0l = *(const bf16x8*)(vplanes + 4194304 + oA);
    bf16x8 a1h = *(const bf16x8*)(vplanes + oB);
    bf16x8 a1l = *(const bf16x8*)(vplanes + 4194304 + oB);

    #pragma unroll 1
    for (int kc = 0; kc < 8; kc++){
        bf16x8 na0h, na0l, na1h, na1l;
        if (kc < 7){
            const __bf16* fnh = vplanes + (size_t)(kc+1) * 8388608;
            const __bf16* fnl = fnh + 4194304;
            na0h = *(const bf16x8*)(fnh + oA);
            na0l = *(const bf16x8*)(fnl + oA);
            na1h = *(const bf16x8*)(fnh + oB);
            na1l = *(const bf16x8*)(fnl + oB);
        } else {
            na0h = a0h; na0l = a0l; na1h = a1h; na1l = a1l;
        }

        const __bf16* wbase  = w2th + (size_t)kc * 4096;
        const __bf16* wlbase = w2tl + (size_t)kc * 4096;
        #pragma unroll
        for (int s = 0; s < 4; s++){
            const __bf16* wb = wbase  + (s*32 + col) * 32 + fragoff;
            const __bf16* wc = wlbase + (s*32 + col) * 32 + fragoff;
            bf16x8 b0h = *(const bf16x8*)(wb);
            bf16x8 b1h = *(const bf16x8*)(wb + 512);
            bf16x8 b0l = *(const bf16x8*)(wc);
            bf16x8 b1l = *(const bf16x8*)(wc + 512);

            acc[s][0] = __builtin_amdgcn_mfma_f32_16x16x32_bf16(a0h, b0h, acc[s][0], 0,0,0);
            acc[s][0] = __builtin_amdgcn_mfma_f32_16x16x32_bf16(a0h, b0l, acc[s][0], 0,0,0);
            acc[s][0] = __builtin_amdgcn_mfma_f32_16x16x32_bf16(a0l, b0h, acc[s][0], 0,0,0);
            acc[s][1] = __builtin_amdgcn_mfma_f32_16x16x32_bf16(a0h, b1h, acc[s][1], 0,0,0);
            acc[s][1] = __builtin_amdgcn_mfma_f32_16x16x32_bf16(a0h, b1l, acc[s][1], 0,0,0);
            acc[s][1] = __builtin_amdgcn_mfma_f32_16x16x32_bf16(a0l, b1h, acc[s][1], 0,0,0);
            acc[s][2] = __builtin_amdgcn_mfma_f32_16x16x32_bf16(a1h, b0h, acc[s][2], 0,0,0);
            acc[s][2] = __builtin_amdgcn_mfma_f32_16x16x32_bf16(a1h, b0l, acc[s][2], 0,0,0);
            acc[s][2] = __builtin_amdgcn_mfma_f32_16x16x32_bf16(a1l, b0h, acc[s][2], 0,0,0);
            acc[s][3] = __builtin_amdgcn_mfma_f32_16x16x32_bf16(a1h, b1h, acc[s][3], 0,0,0);
            acc[s][3] = __builtin_amdgcn_mfma_f32_16x16x32_bf16(a1h, b1l, acc[s][3], 0,0,0);
            acc[s][3] = __builtin_amdgcn_mfma_f32_16x16x32_bf16(a1l, b1h, acc[s][3], 0,0,0);
        }

        a0h = na0h; a0l = na0l; a1h = na1h; a1l = na1l;
    }

    #pragma unroll
    for (int s = 0; s < 4; s++){
        float bl = b2[s*32 + col], bh = b2[s*32 + 16 + col];
        #pragma unroll
        for (int r = 0; r < 4; r++){
            size_t rowA = (size_t)(pbase + kq*4 + r) * 128;
            size_t rowB = (size_t)(pbase + 16 + kq*4 + r) * 128;
            out[rowA + s*32 + col]      = acc[s][0][r] + bl;
            out[rowA + s*32 + 16 + col] = acc[s][1][r] + bh;
            out[rowB + s*32 + col]      = acc[s][2][r] + bl;
            out[rowB + s*32 + 16 + col] = acc[s][3][r] + bh;
        }
    }
}

// ================================================================ FALLBACK PATH (round-9, verbatim; old W layout)
template<int MODE>
__global__ __launch_bounds__(256)
void conv_mfma_kernel(const __bf16* __restrict__ fh, const __bf16* __restrict__ fl,
                      const __bf16* __restrict__ wth, const __bf16* __restrict__ wtl,
                      const float* __restrict__ bias, const int* __restrict__ nbr,
                      const __bf16* __restrict__ r2h, const __bf16* __restrict__ r2l,
                      const float* __restrict__ w2i, const float* __restrict__ b2,
                      __bf16* __restrict__ outh, __bf16* __restrict__ outl,
                      float* __restrict__ out)
{
    __shared__ float vsh[64][33];
    int tid  = threadIdx.x;
    int lane = tid & 63, wid = tid >> 6;
    int pair = wid >> 1;
    int half = wid & 1;
    int col  = lane & 15, kq = lane >> 4;
    int m0   = blockIdx.x * 64 + pair * 32;
    int ptA  = m0 + col, ptB = ptA + 16;
    const int fragoff = kq * 8;

    f32x4 acc00, acc01, acc10, acc11;
    if (half == 0){
        float bv0 = bias[col], bv1 = bias[col + 16];
        acc00 = (f32x4){bv0,bv0,bv0,bv0}; acc01 = (f32x4){bv1,bv1,bv1,bv1};
        acc10 = (f32x4){bv0,bv0,bv0,bv0}; acc11 = (f32x4){bv1,bv1,bv1,bv1};
    } else {
        acc00 = (f32x4){0,0,0,0}; acc01 = (f32x4){0,0,0,0};
        acc10 = (f32x4){0,0,0,0}; acc11 = (f32x4){0,0,0,0};
    }

    int k0 = half ? 14 : 0;
    int k1 = half ? 27 : 14;
    #pragma unroll 1
    for (int k = k0; k < k1; k++){
        int nb0 = nbr[k * MTOT + ptA];
        int nb1 = nbr[k * MTOT + ptB];
        size_t o0 = (size_t)(nb0 < 0 ? 0 : nb0) * 32 + fragoff;
        size_t o1 = (size_t)(nb1 < 0 ? 0 : nb1) * 32 + fragoff;
        bf16x8 a0h = *(const bf16x8*)(fh + o0);
        bf16x8 a0l = *(const bf16x8*)(fl + o0);
        bf16x8 a1h = *(const bf16x8*)(fh + o1);
        bf16x8 a1l = *(const bf16x8*)(fl + o1);
        bf16x8 z = {};
        if (nb0 < 0){ a0h = z; a0l = z; }
        if (nb1 < 0){ a1h = z; a1l = z; }

        const __bf16* wb = wth + (size_t)k*1024 + col*32 + fragoff;
        const __bf16* wc = wtl + (size_t)k*1024 + col*32 + fragoff;
        bf16x8 b0h = *(const bf16x8*)(wb);
        bf16x8 b1h = *(const bf16x8*)(wb + 512);
        bf16x8 b0l = *(const bf16x8*)(wc);
        bf16x8 b1l = *(const bf16x8*)(wc + 512);

        acc00 = __builtin_amdgcn_mfma_f32_16x16x32_bf16(a0h, b0h, acc00, 0,0,0);
        acc00 = __builtin_amdgcn_mfma_f32_16x16x32_bf16(a0h, b0l, acc00, 0,0,0);
        acc00 = __builtin_amdgcn_mfma_f32_16x16x32_bf16(a0l, b0h, acc00, 0,0,0);
        acc01 = __builtin_amdgcn_mfma_f32_16x16x32_bf16(a0h, b1h, acc01, 0,0,0);
        acc01 = __builtin_amdgcn_mfma_f32_16x16x32_bf16(a0h, b1l, acc01, 0,0,0);
        acc01 = __builtin_amdgcn_mfma_f32_16x16x32_bf16(a0l, b1h, acc01, 0,0,0);
        acc10 = __builtin_amdgcn_mfma_f32_16x16x32_bf16(a1h, b0h, acc10, 0,0,0);
        acc10 = __builtin_amdgcn_mfma_f32_16x16x32_bf16(a1h, b0l, acc10, 0,0,0);
        acc10 = __builtin_amdgcn_mfma_f32_16x16x32_bf16(a1l, b0h, acc10, 0,0,0);
        acc11 = __builtin_amdgcn_mfma_f32_16x16x32_bf16(a1h, b1h, acc11, 0,0,0);
        acc11 = __builtin_amdgcn_mfma_f32_16x16x32_bf16(a1h, b1l, acc11, 0,0,0);
        acc11 = __builtin_amdgcn_mfma_f32_16x16x32_bf16(a1l, b1h, acc11, 0,0,0);
    }

    if (half == 1){
        #pragma unroll
        for (int r = 0; r < 4; r++){
            vsh[pair*32 + kq*4 + r][col]           = acc00[r];
            vsh[pair*32 + kq*4 + r][col + 16]      = acc01[r];
            vsh[pair*32 + 16 + kq*4 + r][col]      = acc10[r];
            vsh[pair*32 + 16 + kq*4 + r][col + 16] = acc11[r];
        }
    }
    __syncthreads();
    if (half == 0){
        #pragma unroll
        for (int r = 0; r < 4; r++){
            vsh[pair*32 + kq*4 + r][col]           += acc00[r];
            vsh[pair*32 + kq*4 + r][col + 16]      += acc01[r];
            vsh[pair*32 + 16 + kq*4 + r][col]      += acc10[r];
            vsh[pair*32 + 16 + kq*4 + r][col + 16] += acc11[r];
        }
    }
    __syncthreads();

    if (MODE == 0){
        int eidx = tid * 8;
        int pt = eidx >> 5, c0 = eidx & 31;
        size_t g = (size_t)blockIdx.x * 2048 + eidx;
        bf16x8 rh = *(const bf16x8*)(fh + g);
        bf16x8 rl = *(const bf16x8*)(fl + g);
        bf16x8 oh8, ol8;
        #pragma unroll
        for (int j = 0; j < 8; j++){
            float v = vsh[pt][c0 + j] + (float)rh[j] + (float)rl[j];
            __bf16 hi = (__bf16)v;
            oh8[j] = hi;
            ol8[j] = (__bf16)(v - (float)hi);
        }
        *(bf16x8*)(outh + g) = oh8;
        *(bf16x8*)(outl + g) = ol8;
    } else {
        int eidx = tid * 8;
        int pt = eidx >> 5, c0 = eidx & 31;
        size_t g = (size_t)blockIdx.x * 2048 + eidx;
        bf16x8 rh = *(const bf16x8*)(fh + g);
        bf16x8 rl = *(const bf16x8*)(fl + g);
        bf16x8 sh = *(const bf16x8*)(r2h + g);
        bf16x8 sl = *(const bf16x8*)(r2l + g);
        #pragma unroll
        for (int j = 0; j < 8; j++)
            vsh[pt][c0 + j] += (float)rh[j] + (float)rl[j] + (float)sh[j] + (float)sl[j];
        __syncthreads();

        int pm = tid & 63;
        int tg = __builtin_amdgcn_readfirstlane(tid >> 6);
        size_t m = (size_t)blockIdx.x * 64 + pm;
        float o32[32];
        float* obase = out + m*128 + tg*32;
        if (MODE == 2){
            #pragma unroll
            for (int o = 0; o < 32; o++) o32[o] = b2[tg*32 + o];
        } else {
            #pragma unroll
            for (int q = 0; q < 8; q++){
                float4 t4 = ((const float4*)obase)[q];
                o32[q*4+0] = t4.x; o32[q*4+1] = t4.y; o32[q*4+2] = t4.z; o32[q*4+3] = t4.w;
            }
        }
        #pragma unroll
        for (int c = 0; c < 32; c++){
            float vc = vsh[pm][c];
            const float* w2r = w2i + c*128 + tg*32;
            #pragma unroll
            for (int o = 0; o < 32; o++) o32[o] += vc * w2r[o];
        }
        #pragma unroll
        for (int q = 0; q < 8; q++)
            ((float4*)obase)[q] = make_float4(o32[q*4+0], o32[q*4+1], o32[q*4+2], o32[q*4+3]);
    }
}

// ---------------------------------------------------------------- launch
extern "C" void kernel_launch(void* const* d_in, const int* in_sizes, int n_in,
                              void* d_out, int out_size, void* d_ws, size_t ws_size,
                              hipStream_t stream)
{
    static const int want[9] = {393216, 96, 32, 8192, 256, 442368, 512, 32768, 128};
    const void* bound[9];
    for (int i = 0; i < 9; i++) bound[i] = d_in[i];
    if (n_in == 9){
        for (int i = 0; i < 9; i++)
            for (int j = 0; j < 9; j++)
                if (in_sizes[j] == want[i]) { bound[i] = d_in[j]; break; }
    }
    const float* p      = (const float*)bound[0];
    const float* w1     = (const float*)bound[1];
    const float* b1     = (const float*)bound[2];
    const float* w_mlp  = (const float*)bound[3];
    const float* b_mlp  = (const float*)bound[4];
    const float* w_conv = (const float*)bound[5];
    const float* b_conv = (const float*)bound[6];
    const float* w2     = (const float*)bound[7];
    const float* b2     = (const float*)bound[8];
    float* out = (float*)d_out;

    // Workspace layout (r11): base ~50 MB shared; big path adds 134 MB v planes.
    char* ws = (char*)d_ws;
    __bf16* h0h  = (__bf16*)(ws);
    __bf16* h0l  = (__bf16*)(ws + 8388608);
    __bf16* h1h  = (__bf16*)(ws + 16777216);
    int*    vgrid= (int*)   (ws + 16777216);            // alias of h1h
    __bf16* h1l  = (__bf16*)(ws + 25165824);
    int*    gcbuf= (int*)   (ws + 25165824);            // alias of h1l
    int*    nbr  = (int*)   (ws + 33554432);            // 14,155,776 B
    __bf16* wth  = (__bf16*)(ws + 47710208);            // 884,736 B
    __bf16* wtl  = (__bf16*)(ws + 48594944);            // 884,736 B
    __bf16* w2th = (__bf16*)(ws + 49479680);            // 65,536 B
    __bf16* w2tl = (__bf16*)(ws + 49545216);            // 65,536 B
    float*  pmin = (float*) (ws + 49610752);
    __bf16* vpl  = (__bf16*)(ws + 50331648);            // 8 x 16 MiB v planes

    const bool big = (ws_size >= 184549376ULL);

    static const double GS[8] = {0.01, 0.02, 0.04, 0.08, 0.16, 0.32, 0.64, 1.28};
    static const int    DS[8] = {101, 51, 26, 14, 8, 5, 3, 2};   // ceil(1/g)+1

    pmin_init_kernel<<<1, 64, 0, stream>>>(pmin);
    pmin_kernel<<<dim3(64, 2), 256, 0, stream>>>(p, pmin);
    if (big){
        wcv_wave_kernel<<<1728, 256, 0, stream>>>(w_conv, wth, wtl);
        w2t_kernel<<<128, 256, 0, stream>>>(w2, w2th, w2tl);
    } else {
        wcv_kernel<<<1728, 256, 0, stream>>>(w_conv, wth, wtl);
    }

    for (int i = 0; i < 8; i++){
        int D = DS[i]; double gd = GS[i];
        int ncell = D * D * D;
        hipMemsetAsync(vgrid, 0xFF, (size_t)2*ncell*sizeof(int), stream);
        if (ncell <= 2744)
            scatter_kernel<1><<<MTOT/256, 256, ncell*sizeof(int), stream>>>(p, pmin, vgrid, gcbuf, gd, D);
        else
            scatter_kernel<0><<<MTOT/256, 256, 0, stream>>>(p, pmin, vgrid, gcbuf, gd, D);
        nbr_kernel<<<MTOT/256, 256, 0, stream>>>(gcbuf, vgrid, nbr, D);
        mlp_scale_kernel<<<(MTOT*32)/256, 256, 0, stream>>>(p, w1, b1, w_mlp + i*1024, b_mlp + i*32, h0h, h0l);

        if (big){
            conv4_kernel<0><<<MTOT/32, 256, 0, stream>>>(
                h0h, h0l, wth + (size_t)(2*i)*27648, wtl + (size_t)(2*i)*27648,
                b_conv + (2*i)*32, nbr, nullptr, nullptr, h1h, h1l);
            conv4_kernel<1><<<MTOT/32, 256, 0, stream>>>(
                h1h, h1l, wth + (size_t)(2*i+1)*27648, wtl + (size_t)(2*i+1)*27648,
                b_conv + (2*i+1)*32, nbr, h0h, h0l,
                vpl + (size_t)i*8388608, vpl + (size_t)i*8388608 + 4194304);
        } else {
            conv_mfma_kernel<0><<<MTOT/64, 256, 0, stream>>>(
                h0h, h0l, wth + (size_t)(2*i)*27648, wtl + (size_t)(2*i)*27648,
                b_conv + (2*i)*32, nbr, nullptr, nullptr, nullptr, nullptr,
                h1h, h1l, nullptr);
            if (i == 0)
                conv_mfma_kernel<2><<<MTOT/64, 256, 0, stream>>>(
                    h1h, h1l, wth + (size_t)(2*i+1)*27648, wtl + (size_t)(2*i+1)*27648,
                    b_conv + (2*i+1)*32, nbr, h0h, h0l, w2 + i*32*128, b2,
                    nullptr, nullptr, out);
            else
                conv_mfma_kernel<1><<<MTOT/64, 256, 0, stream>>>(
                    h1h, h1l, wth + (size_t)(2*i+1)*27648, wtl + (size_t)(2*i+1)*27648,
                    b_conv + (2*i+1)*32, nbr, h0h, h0l, w2 + i*32*128, nullptr,
                    nullptr, nullptr, out);
        }
    }
    if (big)
        mlp2_kernel<<<MTOT/128, 256, 0, stream>>>(vpl, w2th, w2tl, b2, out);
}

// Round 14
// 848.318 us; speedup vs baseline: 1.7341x; 1.4301x over previous
//
#include <hip/hip_runtime.h>

#define MTOT 131072   // b*n
#define NB   65536    // n per batch

typedef __attribute__((ext_vector_type(8))) __bf16 bf16x8;
typedef __attribute__((ext_vector_type(4))) __bf16 bf16x4;
typedef __attribute__((ext_vector_type(4))) float  f32x4;

// ---------------------------------------------------------------- pmin
__global__ void pmin_init_kernel(float* pmin){
    if (threadIdx.x < 6) pmin[threadIdx.x] = 2.0f;   // p in [0,1)
}

__global__ void pmin_kernel(const float* __restrict__ p, float* __restrict__ pmin){
    int bi = blockIdx.y;
    float m0 = 2.f, m1 = 2.f, m2 = 2.f;
    for (int ni = blockIdx.x * blockDim.x + threadIdx.x; ni < NB; ni += gridDim.x * blockDim.x){
        const float* pp = p + ((size_t)bi * NB + ni) * 3;
        m0 = fminf(m0, pp[0]); m1 = fminf(m1, pp[1]); m2 = fminf(m2, pp[2]);
    }
    #pragma unroll
    for (int o = 32; o > 0; o >>= 1){
        m0 = fminf(m0, __shfl_down(m0, o, 64));
        m1 = fminf(m1, __shfl_down(m1, o, 64));
        m2 = fminf(m2, __shfl_down(m2, o, 64));
    }
    if ((threadIdx.x & 63) == 0){
        atomicMin((int*)(pmin + bi*3 + 0), __float_as_int(m0));
        atomicMin((int*)(pmin + bi*3 + 1), __float_as_int(m1));
        atomicMin((int*)(pmin + bi*3 + 2), __float_as_int(m2));
    }
}

// ---------------------------------------------------------------- voxel scatter (atomicMax of ids)
// f64 voxelization (floor(p/g) in double) matches the numpy f64 reference bit-exactly.
template<int USE_LDS>
__global__ void scatter_kernel(const float* __restrict__ p, const float* __restrict__ pmin,
                               int* __restrict__ vgrid, int* __restrict__ gcbuf,
                               double gd, int D){
    extern __shared__ int lgrid[];
    int m  = blockIdx.x * blockDim.x + threadIdx.x;
    int bi = m >> 16;
    double px = (double)p[m*3], py = (double)p[m*3+1], pz = (double)p[m*3+2];
    int gx = (int)floor(px / gd) - (int)floor((double)pmin[bi*3+0] / gd);
    int gy = (int)floor(py / gd) - (int)floor((double)pmin[bi*3+1] / gd);
    int gz = (int)floor(pz / gd) - (int)floor((double)pmin[bi*3+2] / gd);
    gcbuf[m] = (gx << 20) | (gy << 10) | gz;
    int cell = (gx * D + gy) * D + gz;

    if (!USE_LDS){
        atomicMax(vgrid + bi * D * D * D + cell, m);
        return;
    }
    int ncell = D * D * D;
    for (int c = threadIdx.x; c < ncell; c += 256) lgrid[c] = -1;
    __syncthreads();
    atomicMax(&lgrid[cell], m);
    __syncthreads();
    int* vg = vgrid + bi * ncell;
    for (int c = threadIdx.x; c < ncell; c += 256){
        int v = lgrid[c];
        if (v >= 0) atomicMax(vg + c, v);
    }
}

// ---------------------------------------------------------------- 27-tap neighbor table (per point; scales 0-1)
__global__ void nbr_kernel(const int* __restrict__ gcbuf, const int* __restrict__ vgrid,
                           int* __restrict__ nbr, int D){
    int m  = blockIdx.x * blockDim.x + threadIdx.x;
    int bi = m >> 16;
    int pk = gcbuf[m];
    int gx = pk >> 20, gy = (pk >> 10) & 1023, gz = pk & 1023;
    #pragma unroll
    for (int k = 0; k < 27; k++){
        int v;
        if (k == 13){
            v = m;
        } else {
            int x = gx + (k/9) - 1;
            int y = gy + ((k/3)%3) - 1;
            int z = gz + (k%3) - 1;
            if (x < 0 || y < 0 || z < 0 || x >= D || y >= D || z >= D) v = -1;
            else v = vgrid[((bi * D + x) * D + y) * D + z];
        }
        nbr[k * MTOT + m] = v;
    }
}

// ---------------------------------------------------------------- 27-tap neighbor table (per CELL; voxel scales)
__global__ void nbrv_kernel(const int* __restrict__ vgrid, int* __restrict__ nbrv,
                            int D, int NC2, int NC2pad){
    int ci = blockIdx.x * 256 + threadIdx.x;
    if (ci >= NC2pad) return;
    int D3 = D * D * D;
    int bi = (ci >= D3) ? 1 : 0;
    int r  = ci - bi * D3;
    int x = r / (D*D), y = (r / D) % D, z = r % D;
    #pragma unroll
    for (int k = 0; k < 27; k++){
        int v = -1;
        if (ci < NC2){
            int nx = x + (k/9) - 1;
            int ny = y + ((k/3)%3) - 1;
            int nz = z + (k%3) - 1;
            if (nx >= 0 && ny >= 0 && nz >= 0 && nx < D && ny < D && nz < D)
                v = vgrid[bi * D3 + ((nx * D + ny) * D + nz)];
        }
        nbrv[k * NC2pad + ci] = v;
    }
}

// ---------------------------------------------------------------- W_conv -> WAVE-LINEAR bf16 hi/lo planes (big path)
// wt2[cv][k][half][l][e] = W[cv][k][ j=(l>>4)*8+e ][ c=half*16+(l&15) ]
__global__ void wcv_wave_kernel(const float* __restrict__ w_conv,
                                __bf16* __restrict__ wth, __bf16* __restrict__ wtl){
    int o = blockIdx.x * 256 + threadIdx.x;          // 442368 total
    int cv = o / 27648, r = o % 27648;
    int k = r / 1024, q = r % 1024;
    int half = q >> 9, t = q & 511;
    int l = t >> 3, e = t & 7;
    int c = half*16 + (l & 15);
    int j = (l >> 4)*8 + e;
    float x = w_conv[cv*27648 + k*1024 + j*32 + c];
    __bf16 hi = (__bf16)x;
    wth[o] = hi;
    wtl[o] = (__bf16)(x - (float)hi);
}

// ---------------------------------------------------------------- W_conv -> [k][c][j] layout (fallback path)
__global__ void wcv_kernel(const float* __restrict__ w_conv,
                           __bf16* __restrict__ wth, __bf16* __restrict__ wtl){
    int o = blockIdx.x * 256 + threadIdx.x;          // 442368 total
    int cv = o / 27648, r = o % 27648;
    int k = r / 1024, q = r % 1024, c = q / 32, j = q % 32;
    float x = w_conv[cv*27648 + k*1024 + j*32 + c];
    __bf16 hi = (__bf16)x;
    wth[o] = hi;
    wtl[o] = (__bf16)(x - (float)hi);
}

// ---------------------------------------------------------------- w2 -> [kc][c(128)][j(32)] bf16 hi/lo
__global__ void w2t_kernel(const float* __restrict__ w2,
                           __bf16* __restrict__ w2th, __bf16* __restrict__ w2tl){
    int o = blockIdx.x * 256 + threadIdx.x;          // 32768 total
    int kc = o >> 12, r = o & 4095, c = r >> 5, j = r & 31;
    float x = w2[(kc*32 + j)*128 + c];
    __bf16 hi = (__bf16)x;
    w2th[o] = hi;
    w2tl[o] = (__bf16)(x - (float)hi);
}

// ---------------------------------------------------------------- fused mlp1 + per-scale mlp -> bf16 hi/lo planes
__global__ void mlp_scale_kernel(const float* __restrict__ p, const float* __restrict__ w1,
                                 const float* __restrict__ b1,
                                 const float* __restrict__ w, const float* __restrict__ b,
                                 __bf16* __restrict__ h0h, __bf16* __restrict__ h0l){
    int t = blockIdx.x * blockDim.x + threadIdx.x;
    int c = t & 31, m = t >> 5;
    float x = p[m*3+0], y = p[m*3+1], z = p[m*3+2];
    float acc = b[c];
    #pragma unroll
    for (int j = 0; j < 32; j++){
        float ptsj = b1[j] + x * w1[j] + y * w1[32 + j] + z * w1[64 + j];
        acc += ptsj * w[j*32 + c];
    }
    __bf16 hi = (__bf16)acc;
    h0h[t] = hi;
    h0l[t] = (__bf16)(acc - (float)hi);
}

// ================================================================ BIG-WS PATH
// conv4 (scales 0-1): 4-way tap split + 2-stage pipeline + wave-linear W.
// MODE 0: h1 planes = conv(f) + f
// MODE 1: v planes  = conv(f) + f + h0
template<int MODE>
__global__ __launch_bounds__(256)
void conv4_kernel(const __bf16* __restrict__ fh, const __bf16* __restrict__ fl,
                  const __bf16* __restrict__ wth, const __bf16* __restrict__ wtl,
                  const float* __restrict__ bias, const int* __restrict__ nbr,
                  const __bf16* __restrict__ r2h, const __bf16* __restrict__ r2l,
                  __bf16* __restrict__ outh, __bf16* __restrict__ outl)
{
    __shared__ float buf0[32][33], buf1[32][33];
    int tid  = threadIdx.x;
    int lane = tid & 63, w = tid >> 6;
    int col  = lane & 15, kq = lane >> 4;
    int ptA  = blockIdx.x * 32 + col, ptB = ptA + 16;
    const int fragoff = kq * 8;

    f32x4 acc00, acc01, acc10, acc11;
    if (w == 0){
        float bv0 = bias[col], bv1 = bias[col + 16];
        acc00 = (f32x4){bv0,bv0,bv0,bv0}; acc01 = (f32x4){bv1,bv1,bv1,bv1};
        acc10 = (f32x4){bv0,bv0,bv0,bv0}; acc11 = (f32x4){bv1,bv1,bv1,bv1};
    } else {
        acc00 = (f32x4){0,0,0,0}; acc01 = (f32x4){0,0,0,0};
        acc10 = (f32x4){0,0,0,0}; acc11 = (f32x4){0,0,0,0};
    }

    int k0 = w * 7, k1 = (k0 + 7 < 27) ? k0 + 7 : 27;

    int idc = nbr[k0 * MTOT + ptA];
    int jdc = nbr[k0 * MTOT + ptB];
    int idn = (k0 + 1 < k1) ? nbr[(k0+1) * MTOT + ptA] : 0;
    int jdn = (k0 + 1 < k1) ? nbr[(k0+1) * MTOT + ptB] : 0;
    size_t oc0 = (size_t)(idc < 0 ? 0 : idc) * 32 + fragoff;
    size_t oc1 = (size_t)(jdc < 0 ? 0 : jdc) * 32 + fragoff;
    bf16x8 a0h = *(const bf16x8*)(fh + oc0);
    bf16x8 a0l = *(const bf16x8*)(fl + oc0);
    bf16x8 a1h = *(const bf16x8*)(fh + oc1);
    bf16x8 a1l = *(const bf16x8*)(fl + oc1);
    bool mc0 = idc < 0, mc1 = jdc < 0;

    #pragma unroll 1
    for (int k = k0; k < k1; k++){
        int idn2 = 0, jdn2 = 0;
        if (k + 2 < k1){ idn2 = nbr[(k+2) * MTOT + ptA]; jdn2 = nbr[(k+2) * MTOT + ptB]; }
        size_t on0 = (size_t)(idn < 0 ? 0 : idn) * 32 + fragoff;
        size_t on1 = (size_t)(jdn < 0 ? 0 : jdn) * 32 + fragoff;
        bf16x8 na0h = *(const bf16x8*)(fh + on0);
        bf16x8 na0l = *(const bf16x8*)(fl + on0);
        bf16x8 na1h = *(const bf16x8*)(fh + on1);
        bf16x8 na1l = *(const bf16x8*)(fl + on1);
        bool nm0 = idn < 0, nm1 = jdn < 0;

        const __bf16* wb = wth + (size_t)k*1024 + lane*8;
        const __bf16* wc = wtl + (size_t)k*1024 + lane*8;
        bf16x8 b0h = *(const bf16x8*)(wb);
        bf16x8 b1h = *(const bf16x8*)(wb + 512);
        bf16x8 b0l = *(const bf16x8*)(wc);
        bf16x8 b1l = *(const bf16x8*)(wc + 512);

        bf16x8 z = {};
        bf16x8 xa0h = mc0 ? z : a0h, xa0l = mc0 ? z : a0l;
        bf16x8 xa1h = mc1 ? z : a1h, xa1l = mc1 ? z : a1l;

        acc00 = __builtin_amdgcn_mfma_f32_16x16x32_bf16(xa0h, b0h, acc00, 0,0,0);
        acc00 = __builtin_amdgcn_mfma_f32_16x16x32_bf16(xa0h, b0l, acc00, 0,0,0);
        acc00 = __builtin_amdgcn_mfma_f32_16x16x32_bf16(xa0l, b0h, acc00, 0,0,0);
        acc01 = __builtin_amdgcn_mfma_f32_16x16x32_bf16(xa0h, b1h, acc01, 0,0,0);
        acc01 = __builtin_amdgcn_mfma_f32_16x16x32_bf16(xa0h, b1l, acc01, 0,0,0);
        acc01 = __builtin_amdgcn_mfma_f32_16x16x32_bf16(xa0l, b1h, acc01, 0,0,0);
        acc10 = __builtin_amdgcn_mfma_f32_16x16x32_bf16(xa1h, b0h, acc10, 0,0,0);
        acc10 = __builtin_amdgcn_mfma_f32_16x16x32_bf16(xa1h, b0l, acc10, 0,0,0);
        acc10 = __builtin_amdgcn_mfma_f32_16x16x32_bf16(xa1l, b0h, acc10, 0,0,0);
        acc11 = __builtin_amdgcn_mfma_f32_16x16x32_bf16(xa1h, b1h, acc11, 0,0,0);
        acc11 = __builtin_amdgcn_mfma_f32_16x16x32_bf16(xa1h, b1l, acc11, 0,0,0);
        acc11 = __builtin_amdgcn_mfma_f32_16x16x32_bf16(xa1l, b1h, acc11, 0,0,0);

        a0h = na0h; a0l = na0l; a1h = na1h; a1l = na1l;
        mc0 = nm0; mc1 = nm1; idn = idn2; jdn = jdn2;
    }

    if (w == 2){
        #pragma unroll
        for (int r = 0; r < 4; r++){
            buf0[kq*4 + r][col]           = acc00[r];
            buf0[kq*4 + r][col + 16]      = acc01[r];
            buf0[16 + kq*4 + r][col]      = acc10[r];
            buf0[16 + kq*4 + r][col + 16] = acc11[r];
        }
    } else if (w == 3){
        #pragma unroll
        for (int r = 0; r < 4; r++){
            buf1[kq*4 + r][col]           = acc00[r];
            buf1[kq*4 + r][col + 16]      = acc01[r];
            buf1[16 + kq*4 + r][col]      = acc10[r];
            buf1[16 + kq*4 + r][col + 16] = acc11[r];
        }
    }
    __syncthreads();
    if (w == 0){
        #pragma unroll
        for (int r = 0; r < 4; r++){
            acc00[r] += buf0[kq*4 + r][col];
            acc01[r] += buf0[kq*4 + r][col + 16];
            acc10[r] += buf0[16 + kq*4 + r][col];
            acc11[r] += buf0[16 + kq*4 + r][col + 16];
        }
    } else if (w == 1){
        #pragma unroll
        for (int r = 0; r < 4; r++){
            acc00[r] += buf1[kq*4 + r][col];
            acc01[r] += buf1[kq*4 + r][col + 16];
            acc10[r] += buf1[16 + kq*4 + r][col];
            acc11[r] += buf1[16 + kq*4 + r][col + 16];
        }
    }
    __syncthreads();
    if (w == 1){
        #pragma unroll
        for (int r = 0; r < 4; r++){
            buf1[kq*4 + r][col]           = acc00[r];
            buf1[kq*4 + r][col + 16]      = acc01[r];
            buf1[16 + kq*4 + r][col]      = acc10[r];
            buf1[16 + kq*4 + r][col + 16] = acc11[r];
        }
    }
    __syncthreads();
    if (w == 0){
        #pragma unroll
        for (int r = 0; r < 4; r++){
            buf0[kq*4 + r][col]           = acc00[r] + buf1[kq*4 + r][col];
            buf0[kq*4 + r][col + 16]      = acc01[r] + buf1[kq*4 + r][col + 16];
            buf0[16 + kq*4 + r][col]      = acc10[r] + buf1[16 + kq*4 + r][col];
            buf0[16 + kq*4 + r][col + 16] = acc11[r] + buf1[16 + kq*4 + r][col + 16];
        }
    }
    __syncthreads();

    int pt = tid >> 3, c0 = (tid & 7) * 4;
    size_t g = (size_t)(blockIdx.x * 32 + pt) * 32 + c0;
    bf16x4 rh = *(const bf16x4*)(fh + g);
    bf16x4 rl = *(const bf16x4*)(fl + g);
    bf16x4 oh4, ol4;
    if (MODE == 0){
        #pragma unroll
        for (int j = 0; j < 4; j++){
            float v = buf0[pt][c0 + j] + (float)rh[j] + (float)rl[j];
            __bf16 hi = (__bf16)v;
            oh4[j] = hi;
            ol4[j] = (__bf16)(v - (float)hi);
        }
    } else {
        bf16x4 sh = *(const bf16x4*)(r2h + g);
        bf16x4 sl = *(const bf16x4*)(r2l + g);
        #pragma unroll
        for (int j = 0; j < 4; j++){
            float v = buf0[pt][c0 + j] + (float)rh[j] + (float)rl[j]
                                       + (float)sh[j] + (float)sl[j];
            __bf16 hi = (__bf16)v;
            oh4[j] = hi;
            ol4[j] = (__bf16)(v - (float)hi);
        }
    }
    *(bf16x4*)(outh + g) = oh4;
    *(bf16x4*)(outl + g) = ol4;
}

// vconv: conv4 over CELLS, 26 taps (k=13 center handled per-point in combine).
// Tap split per wave: w0:0-6, w1:7-12, w2:14-20, w3:21-26. Output f32 vv[cell][32].
__global__ __launch_bounds__(256)
void vconv_kernel(const __bf16* __restrict__ fh, const __bf16* __restrict__ fl,
                  const __bf16* __restrict__ wth, const __bf16* __restrict__ wtl,
                  const float* __restrict__ bias, const int* __restrict__ nbrv,
                  int NC2pad, float* __restrict__ vv)
{
    __shared__ float buf0[32][33], buf1[32][33];
    int tid  = threadIdx.x;
    int lane = tid & 63, w = tid >> 6;
    int col  = lane & 15, kq = lane >> 4;
    int ptA  = blockIdx.x * 32 + col, ptB = ptA + 16;
    const int fragoff = kq * 8;

    f32x4 acc00, acc01, acc10, acc11;
    if (w == 0){
        float bv0 = bias[col], bv1 = bias[col + 16];
        acc00 = (f32x4){bv0,bv0,bv0,bv0}; acc01 = (f32x4){bv1,bv1,bv1,bv1};
        acc10 = (f32x4){bv0,bv0,bv0,bv0}; acc11 = (f32x4){bv1,bv1,bv1,bv1};
    } else {
        acc00 = (f32x4){0,0,0,0}; acc01 = (f32x4){0,0,0,0};
        acc10 = (f32x4){0,0,0,0}; acc11 = (f32x4){0,0,0,0};
    }

    int k0 = (w == 0) ? 0 : (w == 1) ? 7 : (w == 2) ? 14 : 21;
    int k1 = (w == 0) ? 7 : (w == 1) ? 13 : (w == 2) ? 21 : 27;

    int idc = nbrv[k0 * NC2pad + ptA];
    int jdc = nbrv[k0 * NC2pad + ptB];
    int idn = (k0 + 1 < k1) ? nbrv[(k0+1) * NC2pad + ptA] : 0;
    int jdn = (k0 + 1 < k1) ? nbrv[(k0+1) * NC2pad + ptB] : 0;
    size_t oc0 = (size_t)(idc < 0 ? 0 : idc) * 32 + fragoff;
    size_t oc1 = (size_t)(jdc < 0 ? 0 : jdc) * 32 + fragoff;
    bf16x8 a0h = *(const bf16x8*)(fh + oc0);
    bf16x8 a0l = *(const bf16x8*)(fl + oc0);
    bf16x8 a1h = *(const bf16x8*)(fh + oc1);
    bf16x8 a1l = *(const bf16x8*)(fl + oc1);
    bool mc0 = idc < 0, mc1 = jdc < 0;

    #pragma unroll 1
    for (int k = k0; k < k1; k++){
        int idn2 = 0, jdn2 = 0;
        if (k + 2 < k1){ idn2 = nbrv[(k+2) * NC2pad + ptA]; jdn2 = nbrv[(k+2) * NC2pad + ptB]; }
        size_t on0 = (size_t)(idn < 0 ? 0 : idn) * 32 + fragoff;
        size_t on1 = (size_t)(jdn < 0 ? 0 : jdn) * 32 + fragoff;
        bf16x8 na0h = *(const bf16x8*)(fh + on0);
        bf16x8 na0l = *(const bf16x8*)(fl + on0);
        bf16x8 na1h = *(const bf16x8*)(fh + on1);
        bf16x8 na1l = *(const bf16x8*)(fl + on1);
        bool nm0 = idn < 0, nm1 = jdn < 0;

        const __bf16* wb = wth + (size_t)k*1024 + lane*8;
        const __bf16* wc = wtl + (size_t)k*1024 + lane*8;
        bf16x8 b0h = *(const bf16x8*)(wb);
        bf16x8 b1h = *(const bf16x8*)(wb + 512);
        bf16x8 b0l = *(const bf16x8*)(wc);
        bf16x8 b1l = *(const bf16x8*)(wc + 512);

        bf16x8 z = {};
        bf16x8 xa0h = mc0 ? z : a0h, xa0l = mc0 ? z : a0l;
        bf16x8 xa1h = mc1 ? z : a1h, xa1l = mc1 ? z : a1l;

        acc00 = __builtin_amdgcn_mfma_f32_16x16x32_bf16(xa0h, b0h, acc00, 0,0,0);
        acc00 = __builtin_amdgcn_mfma_f32_16x16x32_bf16(xa0h, b0l, acc00, 0,0,0);
        acc00 = __builtin_amdgcn_mfma_f32_16x16x32_bf16(xa0l, b0h, acc00, 0,0,0);
        acc01 = __builtin_amdgcn_mfma_f32_16x16x32_bf16(xa0h, b1h, acc01, 0,0,0);
        acc01 = __builtin_amdgcn_mfma_f32_16x16x32_bf16(xa0h, b1l, acc01, 0,0,0);
        acc01 = __builtin_amdgcn_mfma_f32_16x16x32_bf16(xa0l, b1h, acc01, 0,0,0);
        acc10 = __builtin_amdgcn_mfma_f32_16x16x32_bf16(xa1h, b0h, acc10, 0,0,0);
        acc10 = __builtin_amdgcn_mfma_f32_16x16x32_bf16(xa1h, b0l, acc10, 0,0,0);
        acc10 = __builtin_amdgcn_mfma_f32_16x16x32_bf16(xa1l, b0h, acc10, 0,0,0);
        acc11 = __builtin_amdgcn_mfma_f32_16x16x32_bf16(xa1h, b1h, acc11, 0,0,0);
        acc11 = __builtin_amdgcn_mfma_f32_16x16x32_bf16(xa1h, b1l, acc11, 0,0,0);
        acc11 = __builtin_amdgcn_mfma_f32_16x16x32_bf16(xa1l, b1h, acc11, 0,0,0);

        a0h = na0h; a0l = na0l; a1h = na1h; a1l = na1l;
        mc0 = nm0; mc1 = nm1; idn = idn2; jdn = jdn2;
    }

    if (w == 2){
        #pragma unroll
        for (int r = 0; r < 4; r++){
            buf0[kq*4 + r][col]           = acc00[r];
            buf0[kq*4 + r][col + 16]      = acc01[r];
            buf0[16 + kq*4 + r][col]      = acc10[r];
            buf0[16 + kq*4 + r][col + 16] = acc11[r];
        }
    } else if (w == 3){
        #pragma unroll
        for (int r = 0; r < 4; r++){
            buf1[kq*4 + r][col]           = acc00[r];
            buf1[kq*4 + r][col + 16]      = acc01[r];
            buf1[16 + kq*4 + r][col]      = acc10[r];
            buf1[16 + kq*4 + r][col + 16] = acc11[r];
        }
    }
    __syncthreads();
    if (w == 0){
        #pragma unroll
        for (int r = 0; r < 4; r++){
            acc00[r] += buf0[kq*4 + r][col];
            acc01[r] += buf0[kq*4 + r][col + 16];
            acc10[r] += buf0[16 + kq*4 + r][col];
            acc11[r] += buf0[16 + kq*4 + r][col + 16];
        }
    } else if (w == 1){
        #pragma unroll
        for (int r = 0; r < 4; r++){
            acc00[r] += buf1[kq*4 + r][col];
            acc01[r] += buf1[kq*4 + r][col + 16];
            acc10[r] += buf1[16 + kq*4 + r][col];
            acc11[r] += buf1[16 + kq*4 + r][col + 16];
        }
    }
    __syncthreads();
    if (w == 1){
        #pragma unroll
        for (int r = 0; r < 4; r++){
            buf1[kq*4 + r][col]           = acc00[r];
            buf1[kq*4 + r][col + 16]      = acc01[r];
            buf1[16 + kq*4 + r][col]      = acc10[r];
            buf1[16 + kq*4 + r][col + 16] = acc11[r];
        }
    }
    __syncthreads();
    if (w == 0){
        #pragma unroll
        for (int r = 0; r < 4; r++){
            buf0[kq*4 + r][col]           = acc00[r] + buf1[kq*4 + r][col];
            buf0[kq*4 + r][col + 16]      = acc01[r] + buf1[kq*4 + r][col + 16];
            buf0[16 + kq*4 + r][col]      = acc10[r] + buf1[16 + kq*4 + r][col];
            buf0[16 + kq*4 + r][col + 16] = acc11[r] + buf1[16 + kq*4 + r][col + 16];
        }
    }
    __syncthreads();

    int pt = tid >> 3, c0 = (tid & 7) * 4;
    float* o = vv + (size_t)(blockIdx.x * 32 + pt) * 32 + c0;
    ((float4*)o)[0] = make_float4(buf0[pt][c0], buf0[pt][c0+1], buf0[pt][c0+2], buf0[pt][c0+3]);
}

// combine: per-point center term + voxel-conv gather + residual(s).
// MODE 0: h1[m] = vv[cell(m)] + f[m]@W13 + f[m]              -> h1 planes
// MODE 1: v[m]  = vv[cell(m)] + f[m]@W13 + f[m] + h0[m]      -> v planes
// Block = 4 waves x 32 pts = 128 points. W13 via wave-linear layout (+13*1024).
template<int MODE>
__global__ __launch_bounds__(256)
void combine_kernel(const __bf16* __restrict__ fh, const __bf16* __restrict__ fl,
                    const __bf16* __restrict__ wth, const __bf16* __restrict__ wtl,
                    const float* __restrict__ vv, const int* __restrict__ gcbuf, int D,
                    const __bf16* __restrict__ r2h, const __bf16* __restrict__ r2l,
                    __bf16* __restrict__ outh, __bf16* __restrict__ outl)
{
    __shared__ float vsh[128][33];
    int tid  = threadIdx.x;
    int lane = tid & 63, w = tid >> 6;
    int col  = lane & 15, kq = lane >> 4;
    const int fragoff = kq * 8;
    int mB  = blockIdx.x * 128 + w * 32;
    int ptA = mB + col, ptB = ptA + 16;

    size_t oA = (size_t)ptA * 32 + fragoff;
    size_t oB = (size_t)ptB * 32 + fragoff;
    bf16x8 a0h = *(const bf16x8*)(fh + oA);
    bf16x8 a0l = *(const bf16x8*)(fl + oA);
    bf16x8 a1h = *(const bf16x8*)(fh + oB);
    bf16x8 a1l = *(const bf16x8*)(fl + oB);

    const __bf16* wb = wth + 13*1024 + lane*8;
    const __bf16* wc = wtl + 13*1024 + lane*8;
    bf16x8 b0h = *(const bf16x8*)(wb);
    bf16x8 b1h = *(const bf16x8*)(wb + 512);
    bf16x8 b0l = *(const bf16x8*)(wc);
    bf16x8 b1l = *(const bf16x8*)(wc + 512);

    f32x4 acc00 = {0,0,0,0}, acc01 = {0,0,0,0}, acc10 = {0,0,0,0}, acc11 = {0,0,0,0};
    acc00 = __builtin_amdgcn_mfma_f32_16x16x32_bf16(a0h, b0h, acc00, 0,0,0);
    acc00 = __builtin_amdgcn_mfma_f32_16x16x32_bf16(a0h, b0l, acc00, 0,0,0);
    acc00 = __builtin_amdgcn_mfma_f32_16x16x32_bf16(a0l, b0h, acc00, 0,0,0);
    acc01 = __builtin_amdgcn_mfma_f32_16x16x32_bf16(a0h, b1h, acc01, 0,0,0);
    acc01 = __builtin_amdgcn_mfma_f32_16x16x32_bf16(a0h, b1l, acc01, 0,0,0);
    acc01 = __builtin_amdgcn_mfma_f32_16x16x32_bf16(a0l, b1h, acc01, 0,0,0);
    acc10 = __builtin_amdgcn_mfma_f32_16x16x32_bf16(a1h, b0h, acc10, 0,0,0);
    acc10 = __builtin_amdgcn_mfma_f32_16x16x32_bf16(a1h, b0l, acc10, 0,0,0);
    acc10 = __builtin_amdgcn_mfma_f32_16x16x32_bf16(a1l, b0h, acc10, 0,0,0);
    acc11 = __builtin_amdgcn_mfma_f32_16x16x32_bf16(a1h, b1h, acc11, 0,0,0);
    acc11 = __builtin_amdgcn_mfma_f32_16x16x32_bf16(a1h, b1l, acc11, 0,0,0);
    acc11 = __builtin_amdgcn_mfma_f32_16x16x32_bf16(a1l, b1h, acc11, 0,0,0);

    #pragma unroll
    for (int r = 0; r < 4; r++){
        vsh[w*32 + kq*4 + r][col]           = acc00[r];
        vsh[w*32 + kq*4 + r][col + 16]      = acc01[r];
        vsh[w*32 + 16 + kq*4 + r][col]      = acc10[r];
        vsh[w*32 + 16 + kq*4 + r][col + 16] = acc11[r];
    }
    __syncthreads();

    // epilogue: 128 pts x 32 ch; thread handles 16 elems
    int pt = tid >> 1, c0 = (tid & 1) * 16;
    int m  = blockIdx.x * 128 + pt;
    int pk = gcbuf[m];
    int bi = m >> 16;
    int gx = pk >> 20, gy = (pk >> 10) & 1023, gz = pk & 1023;
    int ci = ((bi * D + gx) * D + gy) * D + gz;

    const float* vrow = vv + (size_t)ci * 32 + c0;
    size_t g = (size_t)m * 32 + c0;
    bf16x8 rh0 = *(const bf16x8*)(fh + g);
    bf16x8 rh1 = *(const bf16x8*)(fh + g + 8);
    bf16x8 rl0 = *(const bf16x8*)(fl + g);
    bf16x8 rl1 = *(const bf16x8*)(fl + g + 8);
    bf16x8 sh0, sh1, sl0, sl1;
    if (MODE == 1){
        sh0 = *(const bf16x8*)(r2h + g);
        sh1 = *(const bf16x8*)(r2h + g + 8);
        sl0 = *(const bf16x8*)(r2l + g);
        sl1 = *(const bf16x8*)(r2l + g + 8);
    }
    bf16x8 oh0, oh1, ol0, ol1;
    #pragma unroll
    for (int j = 0; j < 8; j++){
        float v = vsh[pt][c0 + j] + vrow[j] + (float)rh0[j] + (float)rl0[j];
        if (MODE == 1) v += (float)sh0[j] + (float)sl0[j];
        __bf16 hi = (__bf16)v;
        oh0[j] = hi; ol0[j] = (__bf16)(v - (float)hi);
    }
    #pragma unroll
    for (int j = 0; j < 8; j++){
        float v = vsh[pt][c0 + 8 + j] + vrow[8 + j] + (float)rh1[j] + (float)rl1[j];
        if (MODE == 1) v += (float)sh1[j] + (float)sl1[j];
        __bf16 hi = (__bf16)v;
        oh1[j] = hi; ol1[j] = (__bf16)(v - (float)hi);
    }
    *(bf16x8*)(outh + g)     = oh0;
    *(bf16x8*)(outh + g + 8) = oh1;
    *(bf16x8*)(outl + g)     = ol0;
    *(bf16x8*)(outl + g + 8) = ol1;
}

// mlp2: out[m,128] = b2 + sum_kc v_kc[m,32] @ w2[kc] (3-term hi/lo MFMA).
__global__ __launch_bounds__(256)
void mlp2_kernel(const __bf16* __restrict__ vplanes,
                 const __bf16* __restrict__ w2th, const __bf16* __restrict__ w2tl,
                 const float* __restrict__ b2, float* __restrict__ out)
{
    int tid  = threadIdx.x;
    int lane = tid & 63, w = tid >> 6;
    int col  = lane & 15, kq = lane >> 4;
    const int fragoff = kq * 8;
    int pbase = blockIdx.x * 128 + w * 32;
    size_t oA = (size_t)(pbase + col) * 32 + fragoff;
    size_t oB = (size_t)(pbase + 16 + col) * 32 + fragoff;

    f32x4 acc[4][4];
    #pragma unroll
    for (int s = 0; s < 4; s++)
        #pragma unroll
        for (int q = 0; q < 4; q++) acc[s][q] = (f32x4){0,0,0,0};

    bf16x8 a0h = *(const bf16x8*)(vplanes + oA);
    bf16x8 a0l = *(const bf16x8*)(vplanes + 4194304 + oA);
    bf16x8 a1h = *(const bf16x8*)(vplanes + oB);
    bf16x8 a1l = *(const bf16x8*)(vplanes + 4194304 + oB);

    #pragma unroll 1
    for (int kc = 0; kc < 8; kc++){
        bf16x8 na0h, na0l, na1h, na1l;
        if (kc < 7){
            const __bf16* fnh = vplanes + (size_t)(kc+1) * 8388608;
            const __bf16* fnl = fnh + 4194304;
            na0h = *(const bf16x8*)(fnh + oA);
            na0l = *(const bf16x8*)(fnl + oA);
            na1h = *(const bf16x8*)(fnh + oB);
            na1l = *(const bf16x8*)(fnl + oB);
        } else {
            na0h = a0h; na0l = a0l; na1h = a1h; na1l = a1l;
        }

        const __bf16* wbase  = w2th + (size_t)kc * 4096;
        const __bf16* wlbase = w2tl + (size_t)kc * 4096;
        #pragma unroll
        for (int s = 0; s < 4; s++){
            const __bf16* wb = wbase  + (s*32 + col) * 32 + fragoff;
            const __bf16* wc = wlbase + (s*32 + col) * 32 + fragoff;
            bf16x8 b0h = *(const bf16x8*)(wb);
            bf16x8 b1h = *(const bf16x8*)(wb + 512);
            bf16x8 b0l = *(const bf16x8*)(wc);
            bf16x8 b1l = *(const bf16x8*)(wc + 512);

            acc[s][0] = __builtin_amdgcn_mfma_f32_16x16x32_bf16(a0h, b0h, acc[s][0], 0,0,0);
            acc[s][0] = __builtin_amdgcn_mfma_f32_16x16x32_bf16(a0h, b0l, acc[s][0], 0,0,0);
            acc[s][0] = __builtin_amdgcn_mfma_f32_16x16x32_bf16(a0l, b0h, acc[s][0], 0,0,0);
            acc[s][1] = __builtin_amdgcn_mfma_f32_16x16x32_bf16(a0h, b1h, acc[s][1], 0,0,0);
            acc[s][1] = __builtin_amdgcn_mfma_f32_16x16x32_bf16(a0h, b1l, acc[s][1], 0,0,0);
            acc[s][1] = __builtin_amdgcn_mfma_f32_16x16x32_bf16(a0l, b1h, acc[s][1], 0,0,0);
            acc[s][2] = __builtin_amdgcn_mfma_f32_16x16x32_bf16(a1h, b0h, acc[s][2], 0,0,0);
            acc[s][2] = __builtin_amdgcn_mfma_f32_16x16x32_bf16(a1h, b0l, acc[s][2], 0,0,0);
            acc[s][2] = __builtin_amdgcn_mfma_f32_16x16x32_bf16(a1l, b0h, acc[s][2], 0,0,0);
            acc[s][3] = __builtin_amdgcn_mfma_f32_16x16x32_bf16(a1h, b1h, acc[s][3], 0,0,0);
            acc[s][3] = __builtin_amdgcn_mfma_f32_16x16x32_bf16(a1h, b1l, acc[s][3], 0,0,0);
            acc[s][3] = __builtin_amdgcn_mfma_f32_16x16x32_bf16(a1l, b1h, acc[s][3], 0,0,0);
        }

        a0h = na0h; a0l = na0l; a1h = na1h; a1l = na1l;
    }

    #pragma unroll
    for (int s = 0; s < 4; s++){
        float bl = b2[s*32 + col], bh = b2[s*32 + 16 + col];
        #pragma unroll
        for (int r = 0; r < 4; r++){
            size_t rowA = (size_t)(pbase + kq*4 + r) * 128;
            size_t rowB = (size_t)(pbase + 16 + kq*4 + r) * 128;
            out[rowA + s*32 + col]      = acc[s][0][r] + bl;
            out[rowA + s*32 + 16 + col] = acc[s][1][r] + bh;
            out[rowB + s*32 + col]      = acc[s][2][r] + bl;
            out[rowB + s*32 + 16 + col] = acc[s][3][r] + bh;
        }
    }
}

// ================================================================ FALLBACK PATH (round-9, verbatim; old W layout)
template<int MODE>
__global__ __launch_bounds__(256)
void conv_mfma_kernel(const __bf16* __restrict__ fh, const __bf16* __restrict__ fl,
                      const __bf16* __restrict__ wth, const __bf16* __restrict__ wtl,
                      const float* __restrict__ bias, const int* __restrict__ nbr,
                      const __bf16* __restrict__ r2h, const __bf16* __restrict__ r2l,
                      const float* __restrict__ w2i, const float* __restrict__ b2,
                      __bf16* __restrict__ outh, __bf16* __restrict__ outl,
                      float* __restrict__ out)
{
    __shared__ float vsh[64][33];
    int tid  = threadIdx.x;
    int lane = tid & 63, wid = tid >> 6;
    int pair = wid >> 1;
    int half = wid & 1;
    int col  = lane & 15, kq = lane >> 4;
    int m0   = blockIdx.x * 64 + pair * 32;
    int ptA  = m0 + col, ptB = ptA + 16;
    const int fragoff = kq * 8;

    f32x4 acc00, acc01, acc10, acc11;
    if (half == 0){
        float bv0 = bias[col], bv1 = bias[col + 16];
        acc00 = (f32x4){bv0,bv0,bv0,bv0}; acc01 = (f32x4){bv1,bv1,bv1,bv1};
        acc10 = (f32x4){bv0,bv0,bv0,bv0}; acc11 = (f32x4){bv1,bv1,bv1,bv1};
    } else {
        acc00 = (f32x4){0,0,0,0}; acc01 = (f32x4){0,0,0,0};
        acc10 = (f32x4){0,0,0,0}; acc11 = (f32x4){0,0,0,0};
    }

    int k0 = half ? 14 : 0;
    int k1 = half ? 27 : 14;
    #pragma unroll 1
    for (int k = k0; k < k1; k++){
        int nb0 = nbr[k * MTOT + ptA];
        int nb1 = nbr[k * MTOT + ptB];
        size_t o0 = (size_t)(nb0 < 0 ? 0 : nb0) * 32 + fragoff;
        size_t o1 = (size_t)(nb1 < 0 ? 0 : nb1) * 32 + fragoff;
        bf16x8 a0h = *(const bf16x8*)(fh + o0);
        bf16x8 a0l = *(const bf16x8*)(fl + o0);
        bf16x8 a1h = *(const bf16x8*)(fh + o1);
        bf16x8 a1l = *(const bf16x8*)(fl + o1);
        bf16x8 z = {};
        if (nb0 < 0){ a0h = z; a0l = z; }
        if (nb1 < 0){ a1h = z; a1l = z; }

        const __bf16* wb = wth + (size_t)k*1024 + col*32 + fragoff;
        const __bf16* wc = wtl + (size_t)k*1024 + col*32 + fragoff;
        bf16x8 b0h = *(const bf16x8*)(wb);
        bf16x8 b1h = *(const bf16x8*)(wb + 512);
        bf16x8 b0l = *(const bf16x8*)(wc);
        bf16x8 b1l = *(const bf16x8*)(wc + 512);

        acc00 = __builtin_amdgcn_mfma_f32_16x16x32_bf16(a0h, b0h, acc00, 0,0,0);
        acc00 = __builtin_amdgcn_mfma_f32_16x16x32_bf16(a0h, b0l, acc00, 0,0,0);
        acc00 = __builtin_amdgcn_mfma_f32_16x16x32_bf16(a0l, b0h, acc00, 0,0,0);
        acc01 = __builtin_amdgcn_mfma_f32_16x16x32_bf16(a0h, b1h, acc01, 0,0,0);
        acc01 = __builtin_amdgcn_mfma_f32_16x16x32_bf16(a0h, b1l, acc01, 0,0,0);
        acc01 = __builtin_amdgcn_mfma_f32_16x16x32_bf16(a0l, b1h, acc01, 0,0,0);
        acc10 = __builtin_amdgcn_mfma_f32_16x16x32_bf16(a1h, b0h, acc10, 0,0,0);
        acc10 = __builtin_amdgcn_mfma_f32_16x16x32_bf16(a1h, b0l, acc10, 0,0,0);
        acc10 = __builtin_amdgcn_mfma_f32_16x16x32_bf16(a1l, b0h, acc10, 0,0,0);
        acc11 = __builtin_amdgcn_mfma_f32_16x16x32_bf16(a1h, b1h, acc11, 0,0,0);
        acc11 = __builtin_amdgcn_mfma_f32_16x16x32_bf16(a1h, b1l, acc11, 0,0,0);
        acc11 = __builtin_amdgcn_mfma_f32_16x16x32_bf16(a1l, b1h, acc11, 0,0,0);
    }

    if (half == 1){
        #pragma unroll
        for (int r = 0; r < 4; r++){
            vsh[pair*32 + kq*4 + r][col]           = acc00[r];
            vsh[pair*32 + kq*4 + r][col + 16]      = acc01[r];
            vsh[pair*32 + 16 + kq*4 + r][col]      = acc10[r];
            vsh[pair*32 + 16 + kq*4 + r][col + 16] = acc11[r];
        }
    }
    __syncthreads();
    if (half == 0){
        #pragma unroll
        for (int r = 0; r < 4; r++){
            vsh[pair*32 + kq*4 + r][col]           += acc00[r];
            vsh[pair*32 + kq*4 + r][col + 16]      += acc01[r];
            vsh[pair*32 + 16 + kq*4 + r][col]      += acc10[r];
            vsh[pair*32 + 16 + kq*4 + r][col + 16] += acc11[r];
        }
    }
    __syncthreads();

    if (MODE == 0){
        int eidx = tid * 8;
        int pt = eidx >> 5, c0 = eidx & 31;
        size_t g = (size_t)blockIdx.x * 2048 + eidx;
        bf16x8 rh = *(const bf16x8*)(fh + g);
        bf16x8 rl = *(const bf16x8*)(fl + g);
        bf16x8 oh8, ol8;
        #pragma unroll
        for (int j = 0; j < 8; j++){
            float v = vsh[pt][c0 + j] + (float)rh[j] + (float)rl[j];
            __bf16 hi = (__bf16)v;
            oh8[j] = hi;
            ol8[j] = (__bf16)(v - (float)hi);
        }
        *(bf16x8*)(outh + g) = oh8;
        *(bf16x8*)(outl + g) = ol8;
    } else {
        int eidx = tid * 8;
        int pt = eidx >> 5, c0 = eidx & 31;
        size_t g = (size_t)blockIdx.x * 2048 + eidx;
        bf16x8 rh = *(const bf16x8*)(fh + g);
        bf16x8 rl = *(const bf16x8*)(fl + g);
        bf16x8 sh = *(const bf16x8*)(r2h + g);
        bf16x8 sl = *(const bf16x8*)(r2l + g);
        #pragma unroll
        for (int j = 0; j < 8; j++)
            vsh[pt][c0 + j] += (float)rh[j] + (float)rl[j] + (float)sh[j] + (float)sl[j];
        __syncthreads();

        int pm = tid & 63;
        int tg = __builtin_amdgcn_readfirstlane(tid >> 6);
        size_t m = (size_t)blockIdx.x * 64 + pm;
        float o32[32];
        float* obase = out + m*128 + tg*32;
        if (MODE == 2){
            #pragma unroll
            for (int o = 0; o < 32; o++) o32[o] = b2[tg*32 + o];
        } else {
            #pragma unroll
            for (int q = 0; q < 8; q++){
                float4 t4 = ((const float4*)obase)[q];
                o32[q*4+0] = t4.x; o32[q*4+1] = t4.y; o32[q*4+2] = t4.z; o32[q*4+3] = t4.w;
            }
        }
        #pragma unroll
        for (int c = 0; c < 32; c++){
            float vc = vsh[pm][c];
            const float* w2r = w2i + c*128 + tg*32;
            #pragma unroll
            for (int o = 0; o < 32; o++) o32[o] += vc * w2r[o];
        }
        #pragma unroll
        for (int q = 0; q < 8; q++)
            ((float4*)obase)[q] = make_float4(o32[q*4+0], o32[q*4+1], o32[q*4+2], o32[q*4+3]);
    }
}

// ---------------------------------------------------------------- launch
extern "C" void kernel_launch(void* const* d_in, const int* in_sizes, int n_in,
                              void* d_out, int out_size, void* d_ws, size_t ws_size,
                              hipStream_t stream)
{
    static const int want[9] = {393216, 96, 32, 8192, 256, 442368, 512, 32768, 128};
    const void* bound[9];
    for (int i = 0; i < 9; i++) bound[i] = d_in[i];
    if (n_in == 9){
        for (int i = 0; i < 9; i++)
            for (int j = 0; j < 9; j++)
                if (in_sizes[j] == want[i]) { bound[i] = d_in[j]; break; }
    }
    const float* p      = (const float*)bound[0];
    const float* w1     = (const float*)bound[1];
    const float* b1     = (const float*)bound[2];
    const float* w_mlp  = (const float*)bound[3];
    const float* b_mlp  = (const float*)bound[4];
    const float* w_conv = (const float*)bound[5];
    const float* b_conv = (const float*)bound[6];
    const float* w2     = (const float*)bound[7];
    const float* b2     = (const float*)bound[8];
    float* out = (float*)d_out;

    char* ws = (char*)d_ws;
    __bf16* h0h  = (__bf16*)(ws);
    __bf16* h0l  = (__bf16*)(ws + 8388608);
    __bf16* h1h  = (__bf16*)(ws + 16777216);
    int*    vgrid= (int*)   (ws + 16777216);            // alias of h1h (dead before h1h written)
    __bf16* h1l  = (__bf16*)(ws + 25165824);
    int*    nbr  = (int*)   (ws + 33554432);            // 14,155,776 B (per-point nbr OR nbrv+vv)
    int*    nbrv = (int*)   (ws + 33554432);            //   nbrv: 27*NC2pad ints (<= 3.8 MB)
    float*  vv   = (float*) (ws + 33554432 + 6291456);  //   vv: NC2pad*32 f32 (<= 4.5 MB)
    __bf16* wth  = (__bf16*)(ws + 47710208);            // 884,736 B
    __bf16* wtl  = (__bf16*)(ws + 48594944);            // 884,736 B
    __bf16* w2th = (__bf16*)(ws + 49479680);            // 65,536 B
    __bf16* w2tl = (__bf16*)(ws + 49545216);            // 65,536 B
    float*  pmin = (float*) (ws + 49610752);            // 256 B
    int*    gcbuf= (int*)   (ws + 49612800);            // 524,288 B (dedicated: outlives h1l now)
    __bf16* vpl  = (__bf16*)(ws + 50331648);            // 8 x 16 MiB v planes (big path)

    const bool big = (ws_size >= 184549376ULL);

    static const double GS[8] = {0.01, 0.02, 0.04, 0.08, 0.16, 0.32, 0.64, 1.28};
    static const int    DS[8] = {101, 51, 26, 14, 8, 5, 3, 2};   // ceil(1/g)+1

    pmin_init_kernel<<<1, 64, 0, stream>>>(pmin);
    pmin_kernel<<<dim3(64, 2), 256, 0, stream>>>(p, pmin);
    if (big){
        wcv_wave_kernel<<<1728, 256, 0, stream>>>(w_conv, wth, wtl);
        w2t_kernel<<<128, 256, 0, stream>>>(w2, w2th, w2tl);
    } else {
        wcv_kernel<<<1728, 256, 0, stream>>>(w_conv, wth, wtl);
    }

    for (int i = 0; i < 8; i++){
        int D = DS[i]; double gd = GS[i];
        int ncell = D * D * D;
        int NC2 = 2 * ncell;
        hipMemsetAsync(vgrid, 0xFF, (size_t)NC2*sizeof(int), stream);
        if (ncell <= 2744)
            scatter_kernel<1><<<MTOT/256, 256, ncell*sizeof(int), stream>>>(p, pmin, vgrid, gcbuf, gd, D);
        else
            scatter_kernel<0><<<MTOT/256, 256, 0, stream>>>(p, pmin, vgrid, gcbuf, gd, D);

        const bool voxel = big && (NC2 < MTOT);

        if (voxel){
            int NC2pad = (NC2 + 31) & ~31;
            nbrv_kernel<<<(NC2pad + 255)/256, 256, 0, stream>>>(vgrid, nbrv, D, NC2, NC2pad);
            mlp_scale_kernel<<<(MTOT*32)/256, 256, 0, stream>>>(
                p, w1, b1, w_mlp + i*1024, b_mlp + i*32, h0h, h0l);
            // conv1: voxel conv + per-point combine -> h1 planes
            vconv_kernel<<<NC2pad/32, 256, 0, stream>>>(
                h0h, h0l, wth + (size_t)(2*i)*27648, wtl + (size_t)(2*i)*27648,
                b_conv + (2*i)*32, nbrv, NC2pad, vv);
            combine_kernel<0><<<MTOT/128, 256, 0, stream>>>(
                h0h, h0l, wth + (size_t)(2*i)*27648, wtl + (size_t)(2*i)*27648,
                vv, gcbuf, D, nullptr, nullptr, h1h, h1l);
            // conv2: voxel conv + per-point combine -> v planes
            vconv_kernel<<<NC2pad/32, 256, 0, stream>>>(
                h1h, h1l, wth + (size_t)(2*i+1)*27648, wtl + (size_t)(2*i+1)*27648,
                b_conv + (2*i+1)*32, nbrv, NC2pad, vv);
            combine_kernel<1><<<MTOT/128, 256, 0, stream>>>(
                h1h, h1l, wth + (size_t)(2*i+1)*27648, wtl + (size_t)(2*i+1)*27648,
                vv, gcbuf, D, h0h, h0l,
                vpl + (size_t)i*8388608, vpl + (size_t)i*8388608 + 4194304);
        } else {
            nbr_kernel<<<MTOT/256, 256, 0, stream>>>(gcbuf, vgrid, nbr, D);
            mlp_scale_kernel<<<(MTOT*32)/256, 256, 0, stream>>>(
                p, w1, b1, w_mlp + i*1024, b_mlp + i*32, h0h, h0l);
            if (big){
                conv4_kernel<0><<<MTOT/32, 256, 0, stream>>>(
                    h0h, h0l, wth + (size_t)(2*i)*27648, wtl + (size_t)(2*i)*27648,
                    b_conv + (2*i)*32, nbr, nullptr, nullptr, h1h, h1l);
                conv4_kernel<1><<<MTOT/32, 256, 0, stream>>>(
                    h1h, h1l, wth + (size_t)(2*i+1)*27648, wtl + (size_t)(2*i+1)*27648,
                    b_conv + (2*i+1)*32, nbr, h0h, h0l,
                    vpl + (size_t)i*8388608, vpl + (size_t)i*8388608 + 4194304);
            } else {
                conv_mfma_kernel<0><<<MTOT/64, 256, 0, stream>>>(
                    h0h, h0l, wth + (size_t)(2*i)*27648, wtl + (size_t)(2*i)*27648,
                    b_conv + (2*i)*32, nbr, nullptr, nullptr, nullptr, nullptr,
                    h1h, h1l, nullptr);
                if (i == 0)
                    conv_mfma_kernel<2><<<MTOT/64, 256, 0, stream>>>(
                        h1h, h1l, wth + (size_t)(2*i+1)*27648, wtl + (size_t)(2*i+1)*27648,
                        b_conv + (2*i+1)*32, nbr, h0h, h0l, w2 + i*32*128, b2,
                        nullptr, nullptr, out);
                else
                    conv_mfma_kernel<1><<<MTOT/64, 256, 0, stream>>>(
                        h1h, h1l, wth + (size_t)(2*i+1)*27648, wtl + (size_t)(2*i+1)*27648,
                        b_conv + (2*i+1)*32, nbr, h0h, h0l, w2 + i*32*128, nullptr,
                        nullptr, nullptr, out);
            }
        }
    }
    if (big)
        mlp2_kernel<<<MTOT/128, 256, 0, stream>>>(vpl, w2th, w2tl, b2, out);
}